// Round 16
// baseline (12291.828 us; speedup 1.0000x reference)
//
#include <hip/hip_runtime.h>

#define Bz  16
#define Tz  1024
#define Cz  16
#define Dz  256
#define NHz 4
#define HDz 64
#define Lz  4
#define MROWS (Bz*Tz)   // 16384
#define QB  8           // attention q-rows per block

__device__ __forceinline__ float sigmoidf_(float x){ return 1.0f/(1.0f+__expf(-x)); }
__device__ __forceinline__ float tanh_(float x){
  float e = __expf(2.f*x);
  return 1.f - 2.f/(e + 1.f);
}

// v_dot2_f32_f16: acc += a.x*b.x + a.y*b.y (f16 inputs, f32 accumulate)
__device__ __forceinline__ float dot2f(uint a, uint b, float c){
  float d;
  asm("v_dot2_f32_f16 %0, %1, %2, %3" : "=v"(d) : "v"(a), "v"(b), "v"(c));
  return d;
}
// pack two floats to half2 (RTE)
__device__ __forceinline__ uint f2h2(float a, float b){
  union { _Float16 h[2]; uint u; } r;
  r.h[0] = (_Float16)a; r.h[1] = (_Float16)b;
  return r.u;
}

// 8-lane all-reduce: xor1/xor2 via DPP quad_perm, xor4 via shfl
__device__ __forceinline__ float red8(float a){
  int x = __builtin_amdgcn_update_dpp(0, __float_as_int(a), 0xB1, 0xF, 0xF, true); // quad_perm[1,0,3,2]
  a += __int_as_float(x);
  x = __builtin_amdgcn_update_dpp(0, __float_as_int(a), 0x4E, 0xF, 0xF, true);     // quad_perm[2,3,0,1]
  a += __int_as_float(x);
  a += __shfl_xor(a, 4);
  return a;
}

// lgkm-only barrier: order LDS handoff, never drain the DMA vmcnt queue.
#define BARSYNC() do{ \
  asm volatile("s_waitcnt lgkmcnt(0)" ::: "memory"); \
  __builtin_amdgcn_s_barrier(); \
}while(0)

typedef const __attribute__((address_space(1))) void* as1p;
typedef __attribute__((address_space(3))) void* as3p;

// ---------------------------------------------------------------------------
// Prep: scan weights -> f16 pairs in (i, lane) layout (R7 layout).
// Element (i in [0,16), l in [0,512)): j4=l>>3, ks=l&7, kp=ks*16+i, cols j4*4..+3.
// Also builds biasC[768] = gru_bih + [bhr|bhz|0].
// ---------------------------------------------------------------------------
__global__ __launch_bounds__(256) void k_prep(
    const float* __restrict__ W1, const float* __restrict__ W2, const float* __restrict__ Whh,
    const float* __restrict__ bih, const float* __restrict__ bhh,
    uint* __restrict__ W1L, uint* __restrict__ W2L, uint* __restrict__ WhL,
    float* __restrict__ biasC)
{
  int m = blockIdx.x*256 + threadIdx.x;
  if (m < 65536){
    const float* W = (m < 32768) ? W1 : W2;
    uint* out = (m < 32768) ? W1L : W2L;
    int mm = m & 32767;
    int q = mm >> 2, cc = mm & 3;
    int i = q >> 9, l = q & 511;
    int j4 = l >> 3, ks = l & 7;
    int kp = ks*16 + i;
    int c = j4*4 + cc;
    out[mm] = f2h2(W[(2*kp)*256 + c], W[(2*kp+1)*256 + c]);
  } else if (m < 65536 + 98304){
    int mm = m - 65536;
    int g = mm >> 15;          // gate plane
    int r = mm & 32767;
    int q = r >> 2, cc = r & 3;
    int i = q >> 9, l = q & 511;
    int j4 = l >> 3, ks = l & 7;
    int kp = ks*16 + i;
    int c = j4*4 + cc;
    WhL[mm] = f2h2(Whh[(2*kp)*768 + g*256 + c], Whh[(2*kp+1)*768 + g*256 + c]);
  } else if (m < 65536 + 98304 + 768){
    int c = m - (65536 + 98304);
    biasC[c] = bih[c] + ((c < 512) ? bhh[c] : 0.f);
  }
}

// ---------------------------------------------------------------------------
// K0: per-batch diffusion-step embedding te, FiLM gamma/beta.  grid=B, block=256
// ---------------------------------------------------------------------------
__global__ __launch_bounds__(256) void k_batch_emb(
    const int* __restrict__ t, const float* __restrict__ te_freqs,
    const float* __restrict__ W_temb, const float* __restrict__ b_temb,
    const float* __restrict__ W_film, const float* __restrict__ b_film,
    float* __restrict__ te_out, float* __restrict__ gamma_out, float* __restrict__ beta_out)
{
  int b = blockIdx.x; int j = threadIdx.x;
  __shared__ float s[256];
  __shared__ float ste[256];
  float tf = (float)t[b];
  if (j < 128){
    float targ = tf * te_freqs[j];
    s[j]     = __sinf(targ);
    s[j+128] = __cosf(targ);
  }
  __syncthreads();
  float a0=0,a1=0,a2=0,a3=0;
  #pragma unroll 8
  for (int k=0;k<256;k+=4){
    a0 = fmaf(s[k+0], W_temb[(k+0)*256+j], a0);
    a1 = fmaf(s[k+1], W_temb[(k+1)*256+j], a1);
    a2 = fmaf(s[k+2], W_temb[(k+2)*256+j], a2);
    a3 = fmaf(s[k+3], W_temb[(k+3)*256+j], a3);
  }
  float te = (a0+a1)+(a2+a3) + b_temb[j];
  te_out[b*256+j] = te;
  ste[j] = te * sigmoidf_(te);            // silu
  __syncthreads();
  float g0=0,g1=0,h0=0,h1=0;
  #pragma unroll 8
  for (int k=0;k<256;k+=2){
    float v0 = ste[k+0], v1 = ste[k+1];
    g0 = fmaf(v0, W_film[(k+0)*512+j],     g0);
    g1 = fmaf(v1, W_film[(k+1)*512+j],     g1);
    h0 = fmaf(v0, W_film[(k+0)*512+256+j], h0);
    h1 = fmaf(v1, W_film[(k+1)*512+256+j], h1);
  }
  gamma_out[b*256+j] = g0+g1 + b_film[j];
  beta_out [b*256+j] = h0+h1 + b_film[256+j];
}

// ---------------------------------------------------------------------------
// K1: H0 = sqrt(ab)*relu([x,mask]@W_enc+b) + sqrt(1-ab)*noise + te + FiLM(tm)
// ---------------------------------------------------------------------------
__global__ __launch_bounds__(256) void k_encode(
    const float* __restrict__ x, const float* __restrict__ mask, const float* __restrict__ noise,
    const int* __restrict__ t, const float* __restrict__ alpha_bar, const float* __restrict__ ts,
    const float* __restrict__ W_enc, const float* __restrict__ b_enc,
    const float* __restrict__ th_a, const float* __restrict__ th_b, const float* __restrict__ th_freqs,
    const float* __restrict__ te, const float* __restrict__ gamma, const float* __restrict__ beta,
    float* __restrict__ H0)
{
  int bt = blockIdx.x; int b = bt >> 10;
  int j = threadIdx.x;
  __shared__ float in[32];
  if (j < 16)      in[j] = x[bt*16 + j];
  else if (j < 32) in[j] = mask[bt*16 + (j-16)];
  __syncthreads();
  float acc = 0.f;
  #pragma unroll
  for (int k=0;k<32;k++) acc = fmaf(in[k], W_enc[k*256+j], acc);
  float z = fmaxf(acc + b_enc[j], 0.f);
  float ab = alpha_bar[t[b]];
  float h = sqrtf(ab)*z + sqrtf(1.f-ab)*noise[(size_t)bt*256 + j];
  float tsv = ts[bt];
  float tm;
  if (j & 1){
    int i = (j-1) >> 1;
    tm = fmaf(tsv, th_a[i], th_b[i]);
  } else {
    int m = j >> 2;
    float ph = tsv * th_freqs[m];
    tm = ((j & 3) == 0) ? __sinf(ph) : __cosf(ph);
  }
  tm = fmaf(1.f + gamma[b*256+j], tm, beta[b*256+j]);
  H0[(size_t)bt*256 + j] = h + te[b*256+j] + tm;
}

// ---------------------------------------------------------------------------
// Generic fp32 tiled GEMM (proven): C = A@W + bias [+relu] [+residual]
// ---------------------------------------------------------------------------
template<bool RELU, bool RES>
__global__ __launch_bounds__(256) void k_gemm(
    const float* __restrict__ A, const float* __restrict__ W,
    const float* __restrict__ bias, const float* __restrict__ Rp,
    float* __restrict__ Cp, int M, int N, int K)
{
  __shared__ float As[16][68];
  __shared__ float Bs[16][64];
  int bn = blockIdx.x * 64, bm = blockIdx.y * 64;
  int tid = threadIdx.x;
  int tx = tid & 15, ty = tid >> 4;
  float acc[4][4] = {};
  for (int k0=0; k0<K; k0+=16){
    #pragma unroll
    for (int i=0;i<4;i++){
      int idx = tid + i*256;
      int m = idx >> 4, kk = idx & 15;
      As[kk][m] = A[(size_t)(bm+m)*K + k0+kk];
    }
    #pragma unroll
    for (int i=0;i<4;i++){
      int idx = tid + i*256;
      int kk = idx >> 6, n = idx & 63;
      Bs[kk][n] = W[(size_t)(k0+kk)*N + bn+n];
    }
    __syncthreads();
    #pragma unroll
    for (int kk=0;kk<16;kk++){
      float a0=As[kk][ty*4+0], a1=As[kk][ty*4+1], a2=As[kk][ty*4+2], a3=As[kk][ty*4+3];
      float b0=Bs[kk][tx*4+0], b1=Bs[kk][tx*4+1], b2=Bs[kk][tx*4+2], b3=Bs[kk][tx*4+3];
      acc[0][0]=fmaf(a0,b0,acc[0][0]); acc[0][1]=fmaf(a0,b1,acc[0][1]); acc[0][2]=fmaf(a0,b2,acc[0][2]); acc[0][3]=fmaf(a0,b3,acc[0][3]);
      acc[1][0]=fmaf(a1,b0,acc[1][0]); acc[1][1]=fmaf(a1,b1,acc[1][1]); acc[1][2]=fmaf(a1,b2,acc[1][2]); acc[1][3]=fmaf(a1,b3,acc[1][3]);
      acc[2][0]=fmaf(a2,b0,acc[2][0]); acc[2][1]=fmaf(a2,b1,acc[2][1]); acc[2][2]=fmaf(a2,b2,acc[2][2]); acc[2][3]=fmaf(a2,b3,acc[2][3]);
      acc[3][0]=fmaf(a3,b0,acc[3][0]); acc[3][1]=fmaf(a3,b1,acc[3][1]); acc[3][2]=fmaf(a3,b2,acc[3][2]); acc[3][3]=fmaf(a3,b3,acc[3][3]);
    }
    __syncthreads();
  }
  #pragma unroll
  for (int i=0;i<4;i++){
    int row = bm + ty*4 + i;
    #pragma unroll
    for (int jj=0;jj<4;jj++){
      int col = bn + tx*4 + jj;
      float v = acc[i][jj] + bias[col];
      if (RELU) v = fmaxf(v, 0.f);
      if (RES)  v += Rp[(size_t)row*N + col];
      Cp[(size_t)row*N + col] = v;
    }
  }
}

// ---------------------------------------------------------------------------
// K3: Jump-ODE (Euler) + GRU scan.  grid=B, block=512.
// FULL-STREAM 16-slot/wave DMA ring (128 KB): 64 slices/step = 16 W1 + 48 Whh
// (64 % 16 == 0 -> compile-time slots).  Groups of 4: one vmcnt(8) wait ->
// 4 batched ds_read_b128 -> 16 dot2 -> issue slices +12..+15 into the slots
// consumed LAST group (write-slot never aliases a read since the preceding
// memory-clobbered wait -> no L1-fast-return race, the R12 bug).
// Issue-ahead = 3 groups (~700 cy) >> L2 latency.  W2 register-resident.
// GI/ts flat loads only tighten the conservative vmcnt(8) (never under-wait).
// lgkm-only barriers (3/step).
// ---------------------------------------------------------------------------
#define RING_WAVE_BYTES 16384
#define V2_OFF 131072
#define SCAN_LDS_BYTES (V2_OFF + 1280)

#define WRP(p)  ((p) < 64 ? (p) : (p)-64)
#define SRCP(p) ((p) < 16 ? (W1L4 + (p)*512 + tid) : (WhL4 + ((p)-16)*512 + tid))
#define ISSUE1(pu) __builtin_amdgcn_global_load_lds((as1p)SRCP(WRP(pu)), \
                     (as3p)(ringRd + (((pu)&15)<<10)), 16, 0, 0);

// consume group g (slices 4g..4g+3) into A0..A3 with vector V; refill +12..+15
#define GRP(g, V, A0,A1,A2,A3) { \
  asm volatile("s_waitcnt vmcnt(8)" ::: "memory"); \
  uint4 wv0 = *(const uint4*)(ringRd + (((4*(g)+0)&15)<<10) + lane16); \
  uint4 wv1 = *(const uint4*)(ringRd + (((4*(g)+1)&15)<<10) + lane16); \
  uint4 wv2 = *(const uint4*)(ringRd + (((4*(g)+2)&15)<<10) + lane16); \
  uint4 wv3 = *(const uint4*)(ringRd + (((4*(g)+3)&15)<<10) + lane16); \
  A0=dot2f(wv0.x,(V)[(4*(g)+0)&15],A0); A1=dot2f(wv0.y,(V)[(4*(g)+0)&15],A1); \
  A2=dot2f(wv0.z,(V)[(4*(g)+0)&15],A2); A3=dot2f(wv0.w,(V)[(4*(g)+0)&15],A3); \
  A0=dot2f(wv1.x,(V)[(4*(g)+1)&15],A0); A1=dot2f(wv1.y,(V)[(4*(g)+1)&15],A1); \
  A2=dot2f(wv1.z,(V)[(4*(g)+1)&15],A2); A3=dot2f(wv1.w,(V)[(4*(g)+1)&15],A3); \
  A0=dot2f(wv2.x,(V)[(4*(g)+2)&15],A0); A1=dot2f(wv2.y,(V)[(4*(g)+2)&15],A1); \
  A2=dot2f(wv2.z,(V)[(4*(g)+2)&15],A2); A3=dot2f(wv2.w,(V)[(4*(g)+2)&15],A3); \
  A0=dot2f(wv3.x,(V)[(4*(g)+3)&15],A0); A1=dot2f(wv3.y,(V)[(4*(g)+3)&15],A1); \
  A2=dot2f(wv3.z,(V)[(4*(g)+3)&15],A2); A3=dot2f(wv3.w,(V)[(4*(g)+3)&15],A3); \
  ISSUE1(4*(g)+12) ISSUE1(4*(g)+13) ISSUE1(4*(g)+14) ISSUE1(4*(g)+15) \
}

#define DOT4V(WV, VW) { uint4 _w = (WV); \
  a0 = dot2f(_w.x, VW, a0); a1 = dot2f(_w.y, VW, a1); \
  a2 = dot2f(_w.z, VW, a2); a3 = dot2f(_w.w, VW, a3); }

__global__ __launch_bounds__(512) void k_scan(
    const uint* __restrict__ W1Lg, const uint* __restrict__ W2Lg, const uint* __restrict__ WhLg,
    const float* __restrict__ GI, const float* __restrict__ ts,
    const float* __restrict__ b1, const float* __restrict__ b2,
    const float* __restrict__ bhh, float* __restrict__ Hseq)
{
  extern __shared__ __align__(16) char smem[];
  uint* v2 = (uint*)(smem + V2_OFF);          // ping-pong handoff (2x8x20 words)
  const int tid = threadIdx.x, b = blockIdx.x;
  const int j4 = tid >> 3, ks = tid & 7;
  const int ks5 = ks*5;
  char* ringRd = smem + (tid >> 6)*RING_WAVE_BYTES;   // per-wave 16-slot ring
  const int lane16 = (tid & 63) << 4;
  const uint4* W1L4 = (const uint4*)W1Lg;
  const uint4* W2L4 = (const uint4*)W2Lg;
  const uint4* WhL4 = (const uint4*)WhLg;
  uint4 w2r[16];
  #pragma unroll
  for (int i=0;i<16;i++) w2r[i] = W2L4[i*512 + tid];
  if (tid < 320) v2[tid] = 0u;
  const float4 b1v  = ((const float4*)b1)[j4];
  const float4 b2v  = ((const float4*)b2)[j4];
  const float4 bhnv = ((const float4*)bhh)[128 + j4];
  const float* tsb = ts + b*Tz;
  const float* gib = GI + (size_t)b*Tz*768;
  float* hsq = Hseq + (size_t)b*Tz*256;
  const int wdw = 2*j4;
  const int wslot = (wdw >> 4)*20 + (wdw & 15);
  float4 h = {0.f,0.f,0.f,0.f};
  int cur = 0;
  float tprev = 0.f;
  __syncthreads();   // full drain (w2r/bias loads) before ring DMAs start

  // prime ring: slices 0..11 (all W1) into slots 0..11
  #pragma unroll
  for (int p=0;p<12;p++)
    __builtin_amdgcn_global_load_lds((as1p)(W1L4 + p*512 + tid),
                                     (as3p)(ringRd + (p<<10)), 16, 0, 0);
  float4 gi_r = *(const float4*)(gib + 0*768       + j4*4);
  float4 gi_z = *(const float4*)(gib + 0*768 + 256 + j4*4);
  float4 gi_n = *(const float4*)(gib + 0*768 + 512 + j4*4);

  for (int tt=0; tt<Tz; ++tt){
    float tcur = tsb[tt];
    float dt = tcur - tprev; if (tt == 0) dt = 0.f;
    tprev = tcur;
    uint* bufA = v2 + (cur ? 160 : 0);
    uint* bufB = v2 + (cur ? 0 : 160);
    const uint4* vbA = (const uint4*)bufA;
    const uint4* vbB = (const uint4*)bufB;

    // ---- P1: u = tanh(W1·h + b1), W1 slices 0..15 from ring ----
    {
      uint4 q0=vbA[ks5+0], q1=vbA[ks5+1], q2=vbA[ks5+2], q3=vbA[ks5+3];
      uint vh[16] = {q0.x,q0.y,q0.z,q0.w, q1.x,q1.y,q1.z,q1.w,
                     q2.x,q2.y,q2.z,q2.w, q3.x,q3.y,q3.z,q3.w};
      float a0=0,a1=0,a2=0,a3=0;
      GRP(0, vh, a0,a1,a2,a3)
      GRP(1, vh, a0,a1,a2,a3)
      GRP(2, vh, a0,a1,a2,a3)
      GRP(3, vh, a0,a1,a2,a3)
      a0=red8(a0); a1=red8(a1); a2=red8(a2); a3=red8(a3);
      float u0 = tanh_(a0+b1v.x), u1 = tanh_(a1+b1v.y);
      float u2 = tanh_(a2+b1v.z), u3 = tanh_(a3+b1v.w);
      if (ks == 0){
        uint2 pk; pk.x = f2h2(u0,u1); pk.y = f2h2(u2,u3);
        *(uint2*)(bufB + wslot) = pk;
      }
    }
    BARSYNC();
    // ---- P2: f = W2·u + b2 ; hnew = h + dt·f -> A ----
    float4 hn;
    {
      uint4 p0=vbB[ks5+0], p1=vbB[ks5+1], p2=vbB[ks5+2], p3=vbB[ks5+3];
      uint vu[16] = {p0.x,p0.y,p0.z,p0.w, p1.x,p1.y,p1.z,p1.w,
                     p2.x,p2.y,p2.z,p2.w, p3.x,p3.y,p3.z,p3.w};
      float a0=0,a1=0,a2=0,a3=0;
      #pragma unroll
      for (int i=0;i<16;i++){ DOT4V(w2r[i], vu[i]); }
      a0=red8(a0); a1=red8(a1); a2=red8(a2); a3=red8(a3);
      hn.x = fmaf(dt, a0+b2v.x, h.x);
      hn.y = fmaf(dt, a1+b2v.y, h.y);
      hn.z = fmaf(dt, a2+b2v.z, h.z);
      hn.w = fmaf(dt, a3+b2v.w, h.w);
      if (ks == 0){
        uint2 pk; pk.x = f2h2(hn.x,hn.y); pk.y = f2h2(hn.z,hn.w);
        *(uint2*)(bufA + wslot) = pk;
      }
    }
    BARSYNC();
    // ---- P5: gates = Whh·hnew, slices 16..63 from ring ; h update -> B ----
    {
      uint4 g0=vbA[ks5+0], g1=vbA[ks5+1], g2=vbA[ks5+2], g3=vbA[ks5+3];
      uint vn[16] = {g0.x,g0.y,g0.z,g0.w, g1.x,g1.y,g1.z,g1.w,
                     g2.x,g2.y,g2.z,g2.w, g3.x,g3.y,g3.z,g3.w};
      float r0=0,r1=0,r2=0,r3=0, z0=0,z1=0,z2=0,z3=0, n0=0,n1=0,n2=0,n3=0;
      GRP(4,  vn, r0,r1,r2,r3)
      GRP(5,  vn, r0,r1,r2,r3)
      GRP(6,  vn, r0,r1,r2,r3)
      GRP(7,  vn, r0,r1,r2,r3)
      GRP(8,  vn, z0,z1,z2,z3)
      GRP(9,  vn, z0,z1,z2,z3)
      GRP(10, vn, z0,z1,z2,z3)
      GRP(11, vn, z0,z1,z2,z3)
      GRP(12, vn, n0,n1,n2,n3)
      GRP(13, vn, n0,n1,n2,n3)
      // GI prefetch for step tt+1 (flat loads; only tighten later waits)
      int ttn = (tt+1 < Tz) ? tt+1 : Tz-1;
      float4 ngi_r = *(const float4*)(gib + ttn*768       + j4*4);
      float4 ngi_z = *(const float4*)(gib + ttn*768 + 256 + j4*4);
      float4 ngi_n = *(const float4*)(gib + ttn*768 + 512 + j4*4);
      GRP(14, vn, n0,n1,n2,n3)
      GRP(15, vn, n0,n1,n2,n3)
      r0=red8(r0); r1=red8(r1); r2=red8(r2); r3=red8(r3);
      z0=red8(z0); z1=red8(z1); z2=red8(z2); z3=red8(z3);
      n0=red8(n0); n1=red8(n1); n2=red8(n2); n3=red8(n3);
      // bhr/bhz pre-folded into GI bias
      float gr0 = sigmoidf_(gi_r.x + r0);
      float gr1 = sigmoidf_(gi_r.y + r1);
      float gr2 = sigmoidf_(gi_r.z + r2);
      float gr3 = sigmoidf_(gi_r.w + r3);
      float gz0 = sigmoidf_(gi_z.x + z0);
      float gz1 = sigmoidf_(gi_z.y + z1);
      float gz2 = sigmoidf_(gi_z.z + z2);
      float gz3 = sigmoidf_(gi_z.w + z3);
      float gn0 = tanh_(gi_n.x + gr0*(n0 + bhnv.x));
      float gn1 = tanh_(gi_n.y + gr1*(n1 + bhnv.y));
      float gn2 = tanh_(gi_n.z + gr2*(n2 + bhnv.z));
      float gn3 = tanh_(gi_n.w + gr3*(n3 + bhnv.w));
      h.x = fmaf(gz0, hn.x - gn0, gn0);
      h.y = fmaf(gz1, hn.y - gn1, gn1);
      h.z = fmaf(gz2, hn.z - gn2, gn2);
      h.w = fmaf(gz3, hn.w - gn3, gn3);
      gi_r = ngi_r; gi_z = ngi_z; gi_n = ngi_n;
      if (ks == 0){
        uint2 pk; pk.x = f2h2(h.x,h.y); pk.y = f2h2(h.z,h.w);
        *(uint2*)(bufB + wslot) = pk;
        *(float4*)(hsq + tt*256 + j4*4) = h;
      }
    }
    cur ^= 1;
    BARSYNC();
  }
}

// ---------------------------------------------------------------------------
// K6: causal attention, one (b,h,q-block of 8).  f16-dot2 scores, float4 PV.
// ---------------------------------------------------------------------------
__global__ __launch_bounds__(256) void k_attn(const float* __restrict__ QKV, float* __restrict__ O)
{
  int qb = blockIdx.x & (Tz/QB - 1);
  int bh = blockIdx.x / (Tz/QB);
  int b = bh >> 2, h = bh & 3;
  __shared__ uint Q2[QB][32];
  __shared__ float S[QB][Tz];
  __shared__ __align__(16) char kvbuf[64*68*4];
  __shared__ float rs[QB];
  uint  (*K2)[33] = (uint(*)[33])kvbuf;
  float (*Vs)[68] = (float(*)[68])kvbuf;
  int tid = threadIdx.x;
  const float* base = QKV + (size_t)b*Tz*768;
  for (int i = tid; i < QB*16; i += 256){
    int q = i >> 4, c = i & 15;
    const float4 v = *(const float4*)&base[(size_t)(qb*QB+q)*768 + h*64 + c*4];
    Q2[q][c*2]   = f2h2(v.x*0.125f, v.y*0.125f);
    Q2[q][c*2+1] = f2h2(v.z*0.125f, v.w*0.125f);
  }
  __syncthreads();
  int kmax = qb*QB + QB;
  int nkt = (kmax + 63) >> 6;
  int q = tid >> 5, i0 = tid & 31;
  int qg = qb*QB + q;
  for (int kt=0; kt<nkt; ++kt){
    for (int i=tid; i<64*16; i+=256){
      int r=i>>4, c=i&15;
      const float4 v = *(const float4*)&base[(size_t)(kt*64+r)*768 + 256 + h*64 + c*4];
      K2[r][c*2]   = f2h2(v.x, v.y);
      K2[r][c*2+1] = f2h2(v.z, v.w);
    }
    __syncthreads();
    float a0=0.f, a1=0.f;
    #pragma unroll 8
    for (int dp=0; dp<32; ++dp){
      uint qv = Q2[q][dp];
      a0 = dot2f(K2[i0][dp],    qv, a0);
      a1 = dot2f(K2[i0+32][dp], qv, a1);
    }
    int k0g = kt*64 + i0, k1g = k0g + 32;
    S[q][kt*64+i0]    = (k0g <= qg) ? a0 : -1e30f;
    S[q][kt*64+i0+32] = (k1g <= qg) ? a1 : -1e30f;
    __syncthreads();
  }
  int NK = nkt*64;
  float m = -1e30f;
  for (int kk=i0; kk<NK; kk+=32) m = fmaxf(m, S[q][kk]);
  #pragma unroll
  for (int o=16;o;o>>=1) m = fmaxf(m, __shfl_xor(m, o, 32));
  float sum = 0.f;
  for (int kk=i0; kk<NK; kk+=32){
    float p = __expf(S[q][kk] - m);
    S[q][kk] = p;
    sum += p;
  }
  #pragma unroll
  for (int o=16;o;o>>=1) sum += __shfl_xor(sum, o, 32);
  if (i0 == 0) rs[q] = 1.f/sum;
  int dq = tid & 15;
  int ks = (tid >> 4) & 1;
  float o0=0,o1=0,o2=0,o3=0;
  for (int kt=0; kt<nkt; ++kt){
    __syncthreads();
    for (int i=tid; i<64*16; i+=256){
      int r=i>>4, c=i&15;
      const float4 v = *(const float4*)&base[(size_t)(kt*64+r)*768 + 512 + h*64 + c*4];
      *(float4*)&Vs[r][c*4] = v;
    }
    __syncthreads();
    int kbase = kt*64;
    #pragma unroll 8
    for (int kk=ks; kk<64; kk+=2){
      float p = S[q][kbase+kk];
      const float4 vv = *(const float4*)&Vs[kk][dq*4];
      o0=fmaf(p,vv.x,o0); o1=fmaf(p,vv.y,o1); o2=fmaf(p,vv.z,o2); o3=fmaf(p,vv.w,o3);
    }
  }
  o0 += __shfl_xor(o0, 16); o1 += __shfl_xor(o1, 16);
  o2 += __shfl_xor(o2, 16); o3 += __shfl_xor(o3, 16);
  if (!(tid & 16)){
    float r = rs[q];
    size_t orow = ((size_t)b*Tz + qg)*256 + h*64 + dq*4;
    float4 ov = {o0*r, o1*r, o2*r, o3*r};
    *(float4*)&O[orow] = ov;
  }
}

// ---------------------------------------------------------------------------
// LayerNorm over D=256.
// ---------------------------------------------------------------------------
template<bool FINAL>
__global__ __launch_bounds__(256) void k_ln(
    const float* __restrict__ in, const float* __restrict__ w, const float* __restrict__ bgain,
    const float* __restrict__ addv, float* __restrict__ out)
{
  int row  = blockIdx.x*4 + (threadIdx.x >> 6);
  int lane = threadIdx.x & 63;
  const float4 xv = ((const float4*)(in + (size_t)row*256))[lane];
  float s = xv.x + xv.y + xv.z + xv.w;
  #pragma unroll
  for (int o=32;o;o>>=1) s += __shfl_xor(s, o, 64);
  float mean = s * (1.f/256.f);
  float dx=xv.x-mean, dy=xv.y-mean, dz=xv.z-mean, dw=xv.w-mean;
  float qv = dx*dx + dy*dy + dz*dz + dw*dw;
  #pragma unroll
  for (int o=32;o;o>>=1) qv += __shfl_xor(qv, o, 64);
  float rstd = 1.f/sqrtf(qv*(1.f/256.f) + 1e-5f);
  const float4 wv = ((const float4*)w)[lane];
  const float4 bv = ((const float4*)bgain)[lane];
  float4 ov;
  ov.x = dx*rstd*wv.x + bv.x;
  ov.y = dy*rstd*wv.y + bv.y;
  ov.z = dz*rstd*wv.z + bv.z;
  ov.w = dw*rstd*wv.w + bv.w;
  if (FINAL){
    const float4 av = ((const float4*)(addv + (size_t)row*256))[lane];
    ov.x += av.x; ov.y += av.y; ov.z += av.z; ov.w += av.w;
  }
  ((float4*)(out + (size_t)row*256))[lane] = ov;
}

// ---------------------------------------------------------------------------
extern "C" void kernel_launch(void* const* d_in, const int* in_sizes, int n_in,
                              void* d_out, int out_size, void* d_ws, size_t ws_size,
                              hipStream_t stream)
{
  const float* x         = (const float*)d_in[0];
  const int*   t         = (const int*)  d_in[1];
  const float* ts        = (const float*)d_in[2];
  const float* mask      = (const float*)d_in[3];
  const float* noise     = (const float*)d_in[4];
  const float* alpha_bar = (const float*)d_in[6];
  const float* W_enc     = (const float*)d_in[7];
  const float* b_enc     = (const float*)d_in[8];
  const float* te_freqs  = (const float*)d_in[9];
  const float* W_temb    = (const float*)d_in[10];
  const float* b_temb    = (const float*)d_in[11];
  const float* th_a      = (const float*)d_in[12];
  const float* th_b      = (const float*)d_in[13];
  const float* th_freqs  = (const float*)d_in[14];
  const float* W_film    = (const float*)d_in[15];
  const float* b_film    = (const float*)d_in[16];
  const float* gru_Wih   = (const float*)d_in[17];
  const float* gru_Whh   = (const float*)d_in[18];
  const float* gru_bih   = (const float*)d_in[19];
  const float* gru_bhh   = (const float*)d_in[20];
  const float* ode_W1    = (const float*)d_in[21];
  const float* ode_b1    = (const float*)d_in[22];
  const float* ode_W2    = (const float*)d_in[23];
  const float* ode_b2    = (const float*)d_in[24];
  const float* tr_Wqkv   = (const float*)d_in[25];
  const float* tr_bqkv   = (const float*)d_in[26];
  const float* tr_Wo     = (const float*)d_in[27];
  const float* tr_bo     = (const float*)d_in[28];
  const float* tr_ln1_w  = (const float*)d_in[29];
  const float* tr_ln1_b  = (const float*)d_in[30];
  const float* tr_ln2_w  = (const float*)d_in[31];
  const float* tr_ln2_b  = (const float*)d_in[32];
  const float* tr_W1     = (const float*)d_in[33];
  const float* tr_b1     = (const float*)d_in[34];
  const float* tr_W2     = (const float*)d_in[35];
  const float* tr_b2     = (const float*)d_in[36];
  const float* trn_w     = (const float*)d_in[37];
  const float* trn_b     = (const float*)d_in[38];

  float* w = (float*)d_ws;
  float* te    = w;
  float* gamma = w + 4096;
  float* beta  = w + 8192;
  float* R1    = w + 12288;                 // 16M floats, multi-use
  float* H0    = R1;
  float* GI    = R1 + 4*1024*1024;
  float* QKVb  = R1;
  float* F1    = R1;
  float* Hseq  = R1   + 16*1024*1024;
  float* Ht    = Hseq + 4*1024*1024;
  float* U     = Ht   + 4*1024*1024;
  float* O     = U    + 4*1024*1024;
  uint*  W1L   = (uint*)(O + 4*1024*1024);  // 32768 u32
  uint*  W2L   = W1L + 32768;               // 32768 u32
  uint*  WhL   = W2L + 32768;               // 98304 u32
  float* biasC = (float*)(WhL + 98304);     // 768 floats

  // Phase A
  k_prep<<<643, 256, 0, stream>>>(ode_W1, ode_W2, gru_Whh, gru_bih, gru_bhh,
                                  W1L, W2L, WhL, biasC);
  k_batch_emb<<<Bz, 256, 0, stream>>>(t, te_freqs, W_temb, b_temb, W_film, b_film, te, gamma, beta);
  k_encode<<<MROWS, 256, 0, stream>>>(x, mask, noise, t, alpha_bar, ts, W_enc, b_enc,
                                      th_a, th_b, th_freqs, te, gamma, beta, H0);
  k_gemm<false,false><<<dim3(768/64, MROWS/64), 256, 0, stream>>>(H0, gru_Wih, biasC, nullptr, GI, MROWS, 768, 256);

  // Phase B: scan (129.25 KB dynamic LDS: 128 KB ring + v2)
  hipFuncSetAttribute((const void*)k_scan, hipFuncAttributeMaxDynamicSharedMemorySize, SCAN_LDS_BYTES);
  k_scan<<<Bz, 512, SCAN_LDS_BYTES, stream>>>(W1L, W2L, WhL, GI, ts, ode_b1, ode_b2, gru_bhh, Hseq);

  // Phase C  (layer 0 reads Hseq directly; Ht produced by the first RES gemm)
  for (int l=0; l<Lz; ++l){
    const float* Hin = (l == 0) ? Hseq : Ht;
    k_ln<false><<<MROWS/4, 256, 0, stream>>>(Hin, tr_ln1_w + l*256, tr_ln1_b + l*256, nullptr, U);
    k_gemm<false,false><<<dim3(768/64, MROWS/64), 256, 0, stream>>>(U, tr_Wqkv + (size_t)l*256*768, tr_bqkv + l*768, nullptr, QKVb, MROWS, 768, 256);
    k_attn<<<Bz*NHz*(Tz/QB), 256, 0, stream>>>(QKVb, O);
    k_gemm<false,true><<<dim3(256/64, MROWS/64), 256, 0, stream>>>(O, tr_Wo + (size_t)l*256*256, tr_bo + l*256, Hin, Ht, MROWS, 256, 256);
    k_ln<false><<<MROWS/4, 256, 0, stream>>>(Ht, tr_ln2_w + l*256, tr_ln2_b + l*256, nullptr, U);
    k_gemm<true,false><<<dim3(1024/64, MROWS/64), 256, 0, stream>>>(U, tr_W1 + (size_t)l*256*1024, tr_b1 + l*1024, nullptr, F1, MROWS, 1024, 256);
    k_gemm<false,true><<<dim3(256/64, MROWS/64), 256, 0, stream>>>(F1, tr_W2 + (size_t)l*1024*256, tr_b2 + l*256, Ht, Ht, MROWS, 256, 1024);
  }

  k_ln<true><<<MROWS/4, 256, 0, stream>>>(Ht, trn_w, trn_b, Hseq, (float*)d_out);
}

// Round 17
// 11322.454 us; speedup vs baseline: 1.0856x; 1.0856x over previous
//
#include <hip/hip_runtime.h>

#define Bz  16
#define Tz  1024
#define Cz  16
#define Dz  256
#define NHz 4
#define HDz 64
#define Lz  4
#define MROWS (Bz*Tz)   // 16384
#define QB  8           // attention q-rows per block

__device__ __forceinline__ float sigmoidf_(float x){ return 1.0f/(1.0f+__expf(-x)); }
__device__ __forceinline__ float tanh_(float x){
  float e = __expf(2.f*x);
  return 1.f - 2.f/(e + 1.f);
}

// v_dot2_f32_f16: acc += a.x*b.x + a.y*b.y (f16 inputs, f32 accumulate)
__device__ __forceinline__ float dot2f(uint a, uint b, float c){
  float d;
  asm("v_dot2_f32_f16 %0, %1, %2, %3" : "=v"(d) : "v"(a), "v"(b), "v"(c));
  return d;
}
// pack two floats to half2 (RTE)
__device__ __forceinline__ uint f2h2(float a, float b){
  union { _Float16 h[2]; uint u; } r;
  r.h[0] = (_Float16)a; r.h[1] = (_Float16)b;
  return r.u;
}

// 8-lane all-reduce (R7-proven): xor1/xor2 via DPP quad_perm, xor4 via shfl
__device__ __forceinline__ float red8(float a){
  int x = __builtin_amdgcn_update_dpp(0, __float_as_int(a), 0xB1, 0xF, 0xF, true); // quad_perm[1,0,3,2]
  a += __int_as_float(x);
  x = __builtin_amdgcn_update_dpp(0, __float_as_int(a), 0x4E, 0xF, 0xF, true);     // quad_perm[2,3,0,1]
  a += __int_as_float(x);
  a += __shfl_xor(a, 4);
  return a;
}

// Raw barrier: order LDS handoff only (lgkmcnt) — never drain vmcnt, so the
// Whh DMA ring stays in flight across phases.
#define BARSYNC() do{ \
  asm volatile("s_waitcnt lgkmcnt(0)" ::: "memory"); \
  __builtin_amdgcn_s_barrier(); \
}while(0)

typedef const __attribute__((address_space(1))) void* as1p;
typedef __attribute__((address_space(3))) void* as3p;

// ---------------------------------------------------------------------------
// Prep: scan weights -> f16 pairs in (i, lane) layout (R7 layout).
// Element (i in [0,16), l in [0,512)): j4=l>>3, ks=l&7, kp=ks*16+i, cols j4*4..+3.
// Also builds biasC[768] = gru_bih + [bhr|bhz|0].
// ---------------------------------------------------------------------------
__global__ __launch_bounds__(256) void k_prep(
    const float* __restrict__ W1, const float* __restrict__ W2, const float* __restrict__ Whh,
    const float* __restrict__ bih, const float* __restrict__ bhh,
    uint* __restrict__ W1L, uint* __restrict__ W2L, uint* __restrict__ WhL,
    float* __restrict__ biasC)
{
  int m = blockIdx.x*256 + threadIdx.x;
  if (m < 65536){
    const float* W = (m < 32768) ? W1 : W2;
    uint* out = (m < 32768) ? W1L : W2L;
    int mm = m & 32767;
    int q = mm >> 2, cc = mm & 3;
    int i = q >> 9, l = q & 511;
    int j4 = l >> 3, ks = l & 7;
    int kp = ks*16 + i;
    int c = j4*4 + cc;
    out[mm] = f2h2(W[(2*kp)*256 + c], W[(2*kp+1)*256 + c]);
  } else if (m < 65536 + 98304){
    int mm = m - 65536;
    int g = mm >> 15;          // gate plane
    int r = mm & 32767;
    int q = r >> 2, cc = r & 3;
    int i = q >> 9, l = q & 511;
    int j4 = l >> 3, ks = l & 7;
    int kp = ks*16 + i;
    int c = j4*4 + cc;
    WhL[mm] = f2h2(Whh[(2*kp)*768 + g*256 + c], Whh[(2*kp+1)*768 + g*256 + c]);
  } else if (m < 65536 + 98304 + 768){
    int c = m - (65536 + 98304);
    biasC[c] = bih[c] + ((c < 512) ? bhh[c] : 0.f);
  }
}

// ---------------------------------------------------------------------------
// K0: per-batch diffusion-step embedding te, FiLM gamma/beta.  grid=B, block=256
// ---------------------------------------------------------------------------
__global__ __launch_bounds__(256) void k_batch_emb(
    const int* __restrict__ t, const float* __restrict__ te_freqs,
    const float* __restrict__ W_temb, const float* __restrict__ b_temb,
    const float* __restrict__ W_film, const float* __restrict__ b_film,
    float* __restrict__ te_out, float* __restrict__ gamma_out, float* __restrict__ beta_out)
{
  int b = blockIdx.x; int j = threadIdx.x;
  __shared__ float s[256];
  __shared__ float ste[256];
  float tf = (float)t[b];
  if (j < 128){
    float targ = tf * te_freqs[j];
    s[j]     = __sinf(targ);
    s[j+128] = __cosf(targ);
  }
  __syncthreads();
  float a0=0,a1=0,a2=0,a3=0;
  #pragma unroll 8
  for (int k=0;k<256;k+=4){
    a0 = fmaf(s[k+0], W_temb[(k+0)*256+j], a0);
    a1 = fmaf(s[k+1], W_temb[(k+1)*256+j], a1);
    a2 = fmaf(s[k+2], W_temb[(k+2)*256+j], a2);
    a3 = fmaf(s[k+3], W_temb[(k+3)*256+j], a3);
  }
  float te = (a0+a1)+(a2+a3) + b_temb[j];
  te_out[b*256+j] = te;
  ste[j] = te * sigmoidf_(te);            // silu
  __syncthreads();
  float g0=0,g1=0,h0=0,h1=0;
  #pragma unroll 8
  for (int k=0;k<256;k+=2){
    float v0 = ste[k+0], v1 = ste[k+1];
    g0 = fmaf(v0, W_film[(k+0)*512+j],     g0);
    g1 = fmaf(v1, W_film[(k+1)*512+j],     g1);
    h0 = fmaf(v0, W_film[(k+0)*512+256+j], h0);
    h1 = fmaf(v1, W_film[(k+1)*512+256+j], h1);
  }
  gamma_out[b*256+j] = g0+g1 + b_film[j];
  beta_out [b*256+j] = h0+h1 + b_film[256+j];
}

// ---------------------------------------------------------------------------
// K1: H0 = sqrt(ab)*relu([x,mask]@W_enc+b) + sqrt(1-ab)*noise + te + FiLM(tm)
// ---------------------------------------------------------------------------
__global__ __launch_bounds__(256) void k_encode(
    const float* __restrict__ x, const float* __restrict__ mask, const float* __restrict__ noise,
    const int* __restrict__ t, const float* __restrict__ alpha_bar, const float* __restrict__ ts,
    const float* __restrict__ W_enc, const float* __restrict__ b_enc,
    const float* __restrict__ th_a, const float* __restrict__ th_b, const float* __restrict__ th_freqs,
    const float* __restrict__ te, const float* __restrict__ gamma, const float* __restrict__ beta,
    float* __restrict__ H0)
{
  int bt = blockIdx.x; int b = bt >> 10;
  int j = threadIdx.x;
  __shared__ float in[32];
  if (j < 16)      in[j] = x[bt*16 + j];
  else if (j < 32) in[j] = mask[bt*16 + (j-16)];
  __syncthreads();
  float acc = 0.f;
  #pragma unroll
  for (int k=0;k<32;k++) acc = fmaf(in[k], W_enc[k*256+j], acc);
  float z = fmaxf(acc + b_enc[j], 0.f);
  float ab = alpha_bar[t[b]];
  float h = sqrtf(ab)*z + sqrtf(1.f-ab)*noise[(size_t)bt*256 + j];
  float tsv = ts[bt];
  float tm;
  if (j & 1){
    int i = (j-1) >> 1;
    tm = fmaf(tsv, th_a[i], th_b[i]);
  } else {
    int m = j >> 2;
    float ph = tsv * th_freqs[m];
    tm = ((j & 3) == 0) ? __sinf(ph) : __cosf(ph);
  }
  tm = fmaf(1.f + gamma[b*256+j], tm, beta[b*256+j]);
  H0[(size_t)bt*256 + j] = h + te[b*256+j] + tm;
}

// ---------------------------------------------------------------------------
// GEMM: C = A(MxK) @ W(KxN) + bias [+relu] [+residual], f16-pair dot2 inner.
// 64x64 tile, K-tile 32 (16 f16 pairs). K % 32 == 0.  (R12 kernel, now A/B'd
// against a correct scan: marginal absmax contribution ~0.017-0.05.)
// ---------------------------------------------------------------------------
template<bool RELU, bool RES>
__global__ __launch_bounds__(256) void k_gemm(
    const float* __restrict__ A, const float* __restrict__ W,
    const float* __restrict__ bias, const float* __restrict__ Rp,
    float* __restrict__ Cp, int M, int N, int K)
{
  __shared__ uint As_u[16][68];
  __shared__ uint Bs_u[16][68];
  int bn = blockIdx.x * 64, bm = blockIdx.y * 64;
  int tid = threadIdx.x;
  int tx = tid & 15, ty = tid >> 4;
  float acc[4][4] = {};
  for (int k0=0; k0<K; k0+=32){
    #pragma unroll
    for (int i=0;i<4;i++){
      int idx = tid + i*256;
      int m = idx >> 4, kp = idx & 15;
      const float2 a2 = *(const float2*)&A[(size_t)(bm+m)*K + k0 + 2*kp];
      As_u[kp][m] = f2h2(a2.x, a2.y);
    }
    #pragma unroll
    for (int i=0;i<4;i++){
      int idx = tid + i*256;
      int kp = idx >> 6, n = idx & 63;
      float w0 = W[(size_t)(k0+2*kp  )*N + bn+n];
      float w1 = W[(size_t)(k0+2*kp+1)*N + bn+n];
      Bs_u[kp][n] = f2h2(w0, w1);
    }
    __syncthreads();
    #pragma unroll
    for (int kp=0;kp<16;kp++){
      uint4 av = *(const uint4*)&As_u[kp][ty*4];
      uint4 bv = *(const uint4*)&Bs_u[kp][tx*4];
      acc[0][0]=dot2f(av.x,bv.x,acc[0][0]); acc[0][1]=dot2f(av.x,bv.y,acc[0][1]); acc[0][2]=dot2f(av.x,bv.z,acc[0][2]); acc[0][3]=dot2f(av.x,bv.w,acc[0][3]);
      acc[1][0]=dot2f(av.y,bv.x,acc[1][0]); acc[1][1]=dot2f(av.y,bv.y,acc[1][1]); acc[1][2]=dot2f(av.y,bv.z,acc[1][2]); acc[1][3]=dot2f(av.y,bv.w,acc[1][3]);
      acc[2][0]=dot2f(av.z,bv.x,acc[2][0]); acc[2][1]=dot2f(av.z,bv.y,acc[2][1]); acc[2][2]=dot2f(av.z,bv.z,acc[2][2]); acc[2][3]=dot2f(av.z,bv.w,acc[2][3]);
      acc[3][0]=dot2f(av.w,bv.x,acc[3][0]); acc[3][1]=dot2f(av.w,bv.y,acc[3][1]); acc[3][2]=dot2f(av.w,bv.z,acc[3][2]); acc[3][3]=dot2f(av.w,bv.w,acc[3][3]);
    }
    __syncthreads();
  }
  #pragma unroll
  for (int i=0;i<4;i++){
    int row = bm + ty*4 + i;
    #pragma unroll
    for (int jj=0;jj<4;jj++){
      int col = bn + tx*4 + jj;
      float v = acc[i][jj] + bias[col];
      if (RELU) v = fmaxf(v, 0.f);
      if (RES)  v += Rp[(size_t)row*N + col];
      Cp[(size_t)row*N + col] = v;
    }
  }
}

// ---------------------------------------------------------------------------
// K3: Jump-ODE (Euler) + GRU scan.  grid=B, block=512.  (R15/R10 proven)
// W1 LDS-resident (128 KB).  W2 register-resident (64 VGPR).
// Whh streamed via global_load_lds DMA into a per-wave 3-slot x 1 KB LDS ring.
// 48 slices/step; lgkmcnt-only barriers.
// ---------------------------------------------------------------------------
#define W1_BYTES   131072
#define RING_OFF   131072
#define RING_BYTES 24576          // 8 waves * 3 slots * 1024 B
#define V2_OFF     (RING_OFF + RING_BYTES)
#define SCAN_LDS_BYTES (V2_OFF + 1280)

#define DOT4V(WV, VW) { uint4 _w = (WV); \
  a0 = dot2f(_w.x, VW, a0); a1 = dot2f(_w.y, VW, a1); \
  a2 = dot2f(_w.z, VW, a2); a3 = dot2f(_w.w, VW, a3); }

#define MV16L(VB) { \
  uint4 q0=(VB)[ks5+0], q1=(VB)[ks5+1], q2=(VB)[ks5+2], q3=(VB)[ks5+3]; \
  DOT4V(w1s[0*512+tid], q0.x)  DOT4V(w1s[1*512+tid], q0.y)  DOT4V(w1s[2*512+tid], q0.z)  DOT4V(w1s[3*512+tid], q0.w)  \
  DOT4V(w1s[4*512+tid], q1.x)  DOT4V(w1s[5*512+tid], q1.y)  DOT4V(w1s[6*512+tid], q1.z)  DOT4V(w1s[7*512+tid], q1.w)  \
  DOT4V(w1s[8*512+tid], q2.x)  DOT4V(w1s[9*512+tid], q2.y)  DOT4V(w1s[10*512+tid], q2.z) DOT4V(w1s[11*512+tid], q2.w) \
  DOT4V(w1s[12*512+tid], q3.x) DOT4V(w1s[13*512+tid], q3.y) DOT4V(w1s[14*512+tid], q3.z) DOT4V(w1s[15*512+tid], q3.w) }

#define MV16R(W, VB) { \
  uint4 q0=(VB)[ks5+0], q1=(VB)[ks5+1], q2=(VB)[ks5+2], q3=(VB)[ks5+3]; \
  DOT4V(W[0], q0.x)  DOT4V(W[1], q0.y)  DOT4V(W[2], q0.z)  DOT4V(W[3], q0.w)  \
  DOT4V(W[4], q1.x)  DOT4V(W[5], q1.y)  DOT4V(W[6], q1.z)  DOT4V(W[7], q1.w)  \
  DOT4V(W[8], q2.x)  DOT4V(W[9], q2.y)  DOT4V(W[10], q2.z) DOT4V(W[11], q2.w) \
  DOT4V(W[12], q3.x) DOT4V(W[13], q3.y) DOT4V(W[14], q3.z) DOT4V(W[15], q3.w) }

#define RING_STEP(S, N, G0,G1,G2,G3) { \
  asm volatile("s_waitcnt vmcnt(" #N ")" ::: "memory"); \
  uint4 wv = *(const uint4*)(ringRd + (((S)%3)<<10) + lane16); \
  G0 = dot2f(wv.x, vw[(S)&15], G0); G1 = dot2f(wv.y, vw[(S)&15], G1); \
  G2 = dot2f(wv.z, vw[(S)&15], G2); G3 = dot2f(wv.w, vw[(S)&15], G3); \
  __builtin_amdgcn_global_load_lds((as1p)(WhL4 + ((((S)+3)%48)<<9) + tid), \
                                   (as3p)(ringRd + (((S)%3)<<10)), 16, 0, 0); \
}

__global__ __launch_bounds__(512) void k_scan(
    const uint* __restrict__ W1Lg, const uint* __restrict__ W2Lg, const uint* __restrict__ WhLg,
    const float* __restrict__ GI, const float* __restrict__ ts,
    const float* __restrict__ b1, const float* __restrict__ b2,
    const float* __restrict__ bhh, float* __restrict__ Hseq)
{
  extern __shared__ __align__(16) char smem[];
  uint4* w1s = (uint4*)smem;                 // 128 KB, W1 resident
  uint*  v2  = (uint*)(smem + V2_OFF);       // 2 x 8 chunks x (16 data + 4 pad)
  const int b = blockIdx.x, tid = threadIdx.x;
  const int j4 = tid >> 3, ks = tid & 7;
  const int ks5 = ks*5;
  char* ringRd = smem + RING_OFF + (tid >> 6)*3072;   // per-wave 3-slot ring
  const int lane16 = (tid & 63) << 4;
  const uint4* W1L4 = (const uint4*)W1Lg;
  const uint4* W2L4 = (const uint4*)W2Lg;
  const uint4* WhL4 = (const uint4*)WhLg;
  #pragma unroll
  for (int i=0;i<16;i++) w1s[i*512+tid] = W1L4[i*512+tid];
  uint4 w2r[16];
  #pragma unroll
  for (int i=0;i<16;i++) w2r[i] = W2L4[i*512 + tid];
  if (tid < 320) v2[tid] = 0u;
  const float4 b1v  = ((const float4*)b1)[j4];
  const float4 b2v  = ((const float4*)b2)[j4];
  const float4 bhnv = ((const float4*)bhh)[128 + j4];
  const float* tsb = ts + b*Tz;
  const float* gib = GI + (size_t)b*Tz*768;
  float* hsq = Hseq + (size_t)b*Tz*256;
  const int wdw = 2*j4;
  const int wslot = (wdw >> 4)*20 + (wdw & 15);
  float4 h = {0.f,0.f,0.f,0.f};
  int cur = 0;
  float tprev = 0.f;
  __syncthreads();   // full drain OK here (before any ring DMA)

  // Prologue: prime ring (slices 0..2), then GI for step 0.
  #pragma unroll
  for (int s=0;s<3;s++)
    __builtin_amdgcn_global_load_lds((as1p)(WhL4 + (s<<9) + tid),
                                     (as3p)(ringRd + (s<<10)), 16, 0, 0);
  float4 gi_r = *(const float4*)(gib + 0*768       + j4*4);
  float4 gi_z = *(const float4*)(gib + 0*768 + 256 + j4*4);
  float4 gi_n = *(const float4*)(gib + 0*768 + 512 + j4*4);

  for (int tt=0; tt<Tz; ++tt){
    float tcur = tsb[tt];
    float dt = tcur - tprev; if (tt == 0) dt = 0.f;
    tprev = tcur;
    uint* bufA = v2 + (cur ? 160 : 0);
    uint* bufB = v2 + (cur ? 0 : 160);
    const uint4* vbA = (const uint4*)bufA;
    const uint4* vbB = (const uint4*)bufB;

    // ---- P1: u = tanh(W1·h + b1) -> B ----
    {
      float a0=0,a1=0,a2=0,a3=0;
      MV16L(vbA);
      a0=red8(a0); a1=red8(a1); a2=red8(a2); a3=red8(a3);
      float u0 = tanh_(a0+b1v.x), u1 = tanh_(a1+b1v.y);
      float u2 = tanh_(a2+b1v.z), u3 = tanh_(a3+b1v.w);
      if (ks == 0){
        uint2 pk; pk.x = f2h2(u0,u1); pk.y = f2h2(u2,u3);
        *(uint2*)(bufB + wslot) = pk;
      }
    }
    BARSYNC();
    // ---- P2: f = W2·u + b2 ; hnew = h + dt·f -> A ----
    float4 hn;
    {
      float a0=0,a1=0,a2=0,a3=0;
      MV16R(w2r, vbB);
      a0=red8(a0); a1=red8(a1); a2=red8(a2); a3=red8(a3);
      hn.x = fmaf(dt, a0+b2v.x, h.x);
      hn.y = fmaf(dt, a1+b2v.y, h.y);
      hn.z = fmaf(dt, a2+b2v.z, h.z);
      hn.w = fmaf(dt, a3+b2v.w, h.w);
      if (ks == 0){
        uint2 pk; pk.x = f2h2(hn.x,hn.y); pk.y = f2h2(hn.z,hn.w);
        *(uint2*)(bufA + wslot) = pk;
      }
    }
    BARSYNC();
    // ---- P5: gh = Whh·hnew via DMA ring ; h update -> B ----
    {
      uint4 q0=vbA[ks5+0], q1=vbA[ks5+1], q2=vbA[ks5+2], q3=vbA[ks5+3];
      uint vw[16] = {q0.x,q0.y,q0.z,q0.w, q1.x,q1.y,q1.z,q1.w,
                     q2.x,q2.y,q2.z,q2.w, q3.x,q3.y,q3.z,q3.w};
      float r0=0,r1=0,r2=0,r3=0, z0=0,z1=0,z2=0,z3=0, n0=0,n1=0,n2=0,n3=0;
      RING_STEP(0,3, r0,r1,r2,r3)  RING_STEP(1,3, r0,r1,r2,r3)
      RING_STEP(2,3, r0,r1,r2,r3)  RING_STEP(3,2, r0,r1,r2,r3)
      RING_STEP(4,2, r0,r1,r2,r3)  RING_STEP(5,2, r0,r1,r2,r3)
      RING_STEP(6,2, r0,r1,r2,r3)  RING_STEP(7,2, r0,r1,r2,r3)
      RING_STEP(8,2, r0,r1,r2,r3)  RING_STEP(9,2, r0,r1,r2,r3)
      RING_STEP(10,2, r0,r1,r2,r3) RING_STEP(11,2, r0,r1,r2,r3)
      RING_STEP(12,2, r0,r1,r2,r3) RING_STEP(13,2, r0,r1,r2,r3)
      RING_STEP(14,2, r0,r1,r2,r3) RING_STEP(15,2, r0,r1,r2,r3)
      RING_STEP(16,2, z0,z1,z2,z3) RING_STEP(17,2, z0,z1,z2,z3)
      RING_STEP(18,2, z0,z1,z2,z3) RING_STEP(19,2, z0,z1,z2,z3)
      RING_STEP(20,2, z0,z1,z2,z3) RING_STEP(21,2, z0,z1,z2,z3)
      RING_STEP(22,2, z0,z1,z2,z3) RING_STEP(23,2, z0,z1,z2,z3)
      RING_STEP(24,2, z0,z1,z2,z3) RING_STEP(25,2, z0,z1,z2,z3)
      RING_STEP(26,2, z0,z1,z2,z3) RING_STEP(27,2, z0,z1,z2,z3)
      RING_STEP(28,2, z0,z1,z2,z3) RING_STEP(29,2, z0,z1,z2,z3)
      RING_STEP(30,2, z0,z1,z2,z3) RING_STEP(31,2, z0,z1,z2,z3)
      RING_STEP(32,2, n0,n1,n2,n3) RING_STEP(33,2, n0,n1,n2,n3)
      RING_STEP(34,2, n0,n1,n2,n3) RING_STEP(35,2, n0,n1,n2,n3)
      RING_STEP(36,2, n0,n1,n2,n3) RING_STEP(37,2, n0,n1,n2,n3)
      RING_STEP(38,2, n0,n1,n2,n3) RING_STEP(39,2, n0,n1,n2,n3)
      RING_STEP(40,2, n0,n1,n2,n3) RING_STEP(41,2, n0,n1,n2,n3)
      RING_STEP(42,2, n0,n1,n2,n3) RING_STEP(43,2, n0,n1,n2,n3)
      RING_STEP(44,2, n0,n1,n2,n3)
      int ttn = (tt+1 < Tz) ? tt+1 : Tz-1;
      float4 ngi_r = *(const float4*)(gib + ttn*768       + j4*4);
      float4 ngi_z = *(const float4*)(gib + ttn*768 + 256 + j4*4);
      float4 ngi_n = *(const float4*)(gib + ttn*768 + 512 + j4*4);
      RING_STEP(45,2, n0,n1,n2,n3) RING_STEP(46,2, n0,n1,n2,n3)
      RING_STEP(47,2, n0,n1,n2,n3)
      r0=red8(r0); r1=red8(r1); r2=red8(r2); r3=red8(r3);
      z0=red8(z0); z1=red8(z1); z2=red8(z2); z3=red8(z3);
      n0=red8(n0); n1=red8(n1); n2=red8(n2); n3=red8(n3);
      float gr0 = sigmoidf_(gi_r.x + r0);
      float gr1 = sigmoidf_(gi_r.y + r1);
      float gr2 = sigmoidf_(gi_r.z + r2);
      float gr3 = sigmoidf_(gi_r.w + r3);
      float gz0 = sigmoidf_(gi_z.x + z0);
      float gz1 = sigmoidf_(gi_z.y + z1);
      float gz2 = sigmoidf_(gi_z.z + z2);
      float gz3 = sigmoidf_(gi_z.w + z3);
      float gn0 = tanh_(gi_n.x + gr0*(n0 + bhnv.x));
      float gn1 = tanh_(gi_n.y + gr1*(n1 + bhnv.y));
      float gn2 = tanh_(gi_n.z + gr2*(n2 + bhnv.z));
      float gn3 = tanh_(gi_n.w + gr3*(n3 + bhnv.w));
      h.x = fmaf(gz0, hn.x - gn0, gn0);
      h.y = fmaf(gz1, hn.y - gn1, gn1);
      h.z = fmaf(gz2, hn.z - gn2, gn2);
      h.w = fmaf(gz3, hn.w - gn3, gn3);
      gi_r = ngi_r; gi_z = ngi_z; gi_n = ngi_n;
      if (ks == 0){
        uint2 pk; pk.x = f2h2(h.x,h.y); pk.y = f2h2(h.z,h.w);
        *(uint2*)(bufB + wslot) = pk;
        *(float4*)(hsq + tt*256 + j4*4) = h;
      }
    }
    cur ^= 1;
    BARSYNC();
  }
}

// ---------------------------------------------------------------------------
// K6: causal attention, one (b,h,q-block of 8).  f16-dot2 scores, float4 PV.
// ---------------------------------------------------------------------------
__global__ __launch_bounds__(256) void k_attn(const float* __restrict__ QKV, float* __restrict__ O)
{
  int qb = blockIdx.x & (Tz/QB - 1);
  int bh = blockIdx.x / (Tz/QB);
  int b = bh >> 2, h = bh & 3;
  __shared__ uint Q2[QB][32];
  __shared__ float S[QB][Tz];
  __shared__ __align__(16) char kvbuf[64*68*4];
  __shared__ float rs[QB];
  uint  (*K2)[33] = (uint(*)[33])kvbuf;
  float (*Vs)[68] = (float(*)[68])kvbuf;
  int tid = threadIdx.x;
  const float* base = QKV + (size_t)b*Tz*768;
  for (int i = tid; i < QB*16; i += 256){
    int q = i >> 4, c = i & 15;
    const float4 v = *(const float4*)&base[(size_t)(qb*QB+q)*768 + h*64 + c*4];
    Q2[q][c*2]   = f2h2(v.x*0.125f, v.y*0.125f);
    Q2[q][c*2+1] = f2h2(v.z*0.125f, v.w*0.125f);
  }
  __syncthreads();
  int kmax = qb*QB + QB;
  int nkt = (kmax + 63) >> 6;
  int q = tid >> 5, i0 = tid & 31;
  int qg = qb*QB + q;
  for (int kt=0; kt<nkt; ++kt){
    for (int i=tid; i<64*16; i+=256){
      int r=i>>4, c=i&15;
      const float4 v = *(const float4*)&base[(size_t)(kt*64+r)*768 + 256 + h*64 + c*4];
      K2[r][c*2]   = f2h2(v.x, v.y);
      K2[r][c*2+1] = f2h2(v.z, v.w);
    }
    __syncthreads();
    float a0=0.f, a1=0.f;
    #pragma unroll 8
    for (int dp=0; dp<32; ++dp){
      uint qv = Q2[q][dp];
      a0 = dot2f(K2[i0][dp],    qv, a0);
      a1 = dot2f(K2[i0+32][dp], qv, a1);
    }
    int k0g = kt*64 + i0, k1g = k0g + 32;
    S[q][kt*64+i0]    = (k0g <= qg) ? a0 : -1e30f;
    S[q][kt*64+i0+32] = (k1g <= qg) ? a1 : -1e30f;
    __syncthreads();
  }
  int NK = nkt*64;
  float m = -1e30f;
  for (int kk=i0; kk<NK; kk+=32) m = fmaxf(m, S[q][kk]);
  #pragma unroll
  for (int o=16;o;o>>=1) m = fmaxf(m, __shfl_xor(m, o, 32));
  float sum = 0.f;
  for (int kk=i0; kk<NK; kk+=32){
    float p = __expf(S[q][kk] - m);
    S[q][kk] = p;
    sum += p;
  }
  #pragma unroll
  for (int o=16;o;o>>=1) sum += __shfl_xor(sum, o, 32);
  if (i0 == 0) rs[q] = 1.f/sum;
  int dq = tid & 15;
  int ks = (tid >> 4) & 1;
  float o0=0,o1=0,o2=0,o3=0;
  for (int kt=0; kt<nkt; ++kt){
    __syncthreads();
    for (int i=tid; i<64*16; i+=256){
      int r=i>>4, c=i&15;
      const float4 v = *(const float4*)&base[(size_t)(kt*64+r)*768 + 512 + h*64 + c*4];
      *(float4*)&Vs[r][c*4] = v;
    }
    __syncthreads();
    int kbase = kt*64;
    #pragma unroll 8
    for (int kk=ks; kk<64; kk+=2){
      float p = S[q][kbase+kk];
      const float4 vv = *(const float4*)&Vs[kk][dq*4];
      o0=fmaf(p,vv.x,o0); o1=fmaf(p,vv.y,o1); o2=fmaf(p,vv.z,o2); o3=fmaf(p,vv.w,o3);
    }
  }
  o0 += __shfl_xor(o0, 16); o1 += __shfl_xor(o1, 16);
  o2 += __shfl_xor(o2, 16); o3 += __shfl_xor(o3, 16);
  if (!(tid & 16)){
    float r = rs[q];
    size_t orow = ((size_t)b*Tz + qg)*256 + h*64 + dq*4;
    float4 ov = {o0*r, o1*r, o2*r, o3*r};
    *(float4*)&O[orow] = ov;
  }
}

// ---------------------------------------------------------------------------
// LayerNorm over D=256.
// ---------------------------------------------------------------------------
template<bool FINAL>
__global__ __launch_bounds__(256) void k_ln(
    const float* __restrict__ in, const float* __restrict__ w, const float* __restrict__ bgain,
    const float* __restrict__ addv, float* __restrict__ out)
{
  int row  = blockIdx.x*4 + (threadIdx.x >> 6);
  int lane = threadIdx.x & 63;
  const float4 xv = ((const float4*)(in + (size_t)row*256))[lane];
  float s = xv.x + xv.y + xv.z + xv.w;
  #pragma unroll
  for (int o=32;o;o>>=1) s += __shfl_xor(s, o, 64);
  float mean = s * (1.f/256.f);
  float dx=xv.x-mean, dy=xv.y-mean, dz=xv.z-mean, dw=xv.w-mean;
  float qv = dx*dx + dy*dy + dz*dz + dw*dw;
  #pragma unroll
  for (int o=32;o;o>>=1) qv += __shfl_xor(qv, o, 64);
  float rstd = 1.f/sqrtf(qv*(1.f/256.f) + 1e-5f);
  const float4 wv = ((const float4*)w)[lane];
  const float4 bv = ((const float4*)bgain)[lane];
  float4 ov;
  ov.x = dx*rstd*wv.x + bv.x;
  ov.y = dy*rstd*wv.y + bv.y;
  ov.z = dz*rstd*wv.z + bv.z;
  ov.w = dw*rstd*wv.w + bv.w;
  if (FINAL){
    const float4 av = ((const float4*)(addv + (size_t)row*256))[lane];
    ov.x += av.x; ov.y += av.y; ov.z += av.z; ov.w += av.w;
  }
  ((float4*)(out + (size_t)row*256))[lane] = ov;
}

// ---------------------------------------------------------------------------
extern "C" void kernel_launch(void* const* d_in, const int* in_sizes, int n_in,
                              void* d_out, int out_size, void* d_ws, size_t ws_size,
                              hipStream_t stream)
{
  const float* x         = (const float*)d_in[0];
  const int*   t         = (const int*)  d_in[1];
  const float* ts        = (const float*)d_in[2];
  const float* mask      = (const float*)d_in[3];
  const float* noise     = (const float*)d_in[4];
  const float* alpha_bar = (const float*)d_in[6];
  const float* W_enc     = (const float*)d_in[7];
  const float* b_enc     = (const float*)d_in[8];
  const float* te_freqs  = (const float*)d_in[9];
  const float* W_temb    = (const float*)d_in[10];
  const float* b_temb    = (const float*)d_in[11];
  const float* th_a      = (const float*)d_in[12];
  const float* th_b      = (const float*)d_in[13];
  const float* th_freqs  = (const float*)d_in[14];
  const float* W_film    = (const float*)d_in[15];
  const float* b_film    = (const float*)d_in[16];
  const float* gru_Wih   = (const float*)d_in[17];
  const float* gru_Whh   = (const float*)d_in[18];
  const float* gru_bih   = (const float*)d_in[19];
  const float* gru_bhh   = (const float*)d_in[20];
  const float* ode_W1    = (const float*)d_in[21];
  const float* ode_b1    = (const float*)d_in[22];
  const float* ode_W2    = (const float*)d_in[23];
  const float* ode_b2    = (const float*)d_in[24];
  const float* tr_Wqkv   = (const float*)d_in[25];
  const float* tr_bqkv   = (const float*)d_in[26];
  const float* tr_Wo     = (const float*)d_in[27];
  const float* tr_bo     = (const float*)d_in[28];
  const float* tr_ln1_w  = (const float*)d_in[29];
  const float* tr_ln1_b  = (const float*)d_in[30];
  const float* tr_ln2_w  = (const float*)d_in[31];
  const float* tr_ln2_b  = (const float*)d_in[32];
  const float* tr_W1     = (const float*)d_in[33];
  const float* tr_b1     = (const float*)d_in[34];
  const float* tr_W2     = (const float*)d_in[35];
  const float* tr_b2     = (const float*)d_in[36];
  const float* trn_w     = (const float*)d_in[37];
  const float* trn_b     = (const float*)d_in[38];

  float* w = (float*)d_ws;
  float* te    = w;
  float* gamma = w + 4096;
  float* beta  = w + 8192;
  float* R1    = w + 12288;                 // 16M floats, multi-use
  float* H0    = R1;
  float* GI    = R1 + 4*1024*1024;
  float* QKVb  = R1;
  float* F1    = R1;
  float* Hseq  = R1   + 16*1024*1024;
  float* Ht    = Hseq + 4*1024*1024;
  float* U     = Ht   + 4*1024*1024;
  float* O     = U    + 4*1024*1024;
  uint*  W1L   = (uint*)(O + 4*1024*1024);  // 32768 u32
  uint*  W2L   = W1L + 32768;               // 32768 u32
  uint*  WhL   = W2L + 32768;               // 98304 u32
  float* biasC = (float*)(WhL + 98304);     // 768 floats

  // Phase A
  k_prep<<<643, 256, 0, stream>>>(ode_W1, ode_W2, gru_Whh, gru_bih, gru_bhh,
                                  W1L, W2L, WhL, biasC);
  k_batch_emb<<<Bz, 256, 0, stream>>>(t, te_freqs, W_temb, b_temb, W_film, b_film, te, gamma, beta);
  k_encode<<<MROWS, 256, 0, stream>>>(x, mask, noise, t, alpha_bar, ts, W_enc, b_enc,
                                      th_a, th_b, th_freqs, te, gamma, beta, H0);
  k_gemm<false,false><<<dim3(768/64, MROWS/64), 256, 0, stream>>>(H0, gru_Wih, biasC, nullptr, GI, MROWS, 768, 256);

  // Phase B: scan (153.25 KB dynamic LDS)
  hipFuncSetAttribute((const void*)k_scan, hipFuncAttributeMaxDynamicSharedMemorySize, SCAN_LDS_BYTES);
  k_scan<<<Bz, 512, SCAN_LDS_BYTES, stream>>>(W1L, W2L, WhL, GI, ts, ode_b1, ode_b2, gru_bhh, Hseq);

  // Phase C  (layer 0 reads Hseq directly; Ht produced by the first RES gemm)
  for (int l=0; l<Lz; ++l){
    const float* Hin = (l == 0) ? Hseq : Ht;
    k_ln<false><<<MROWS/4, 256, 0, stream>>>(Hin, tr_ln1_w + l*256, tr_ln1_b + l*256, nullptr, U);
    k_gemm<false,false><<<dim3(768/64, MROWS/64), 256, 0, stream>>>(U, tr_Wqkv + (size_t)l*256*768, tr_bqkv + l*768, nullptr, QKVb, MROWS, 768, 256);
    k_attn<<<Bz*NHz*(Tz/QB), 256, 0, stream>>>(QKVb, O);
    k_gemm<false,true><<<dim3(256/64, MROWS/64), 256, 0, stream>>>(O, tr_Wo + (size_t)l*256*256, tr_bo + l*256, Hin, Ht, MROWS, 256, 256);
    k_ln<false><<<MROWS/4, 256, 0, stream>>>(Ht, tr_ln2_w + l*256, tr_ln2_b + l*256, nullptr, U);
    k_gemm<true,false><<<dim3(1024/64, MROWS/64), 256, 0, stream>>>(U, tr_W1 + (size_t)l*256*1024, tr_b1 + l*1024, nullptr, F1, MROWS, 1024, 256);
    k_gemm<false,true><<<dim3(256/64, MROWS/64), 256, 0, stream>>>(F1, tr_W2 + (size_t)l*1024*256, tr_b2 + l*256, Ht, Ht, MROWS, 256, 1024);
  }

  k_ln<true><<<MROWS/4, 256, 0, stream>>>(Ht, trn_w, trn_b, Hseq, (float*)d_out);
}

// Round 18
// 10437.805 us; speedup vs baseline: 1.1776x; 1.0848x over previous
//
#include <hip/hip_runtime.h>

#define Bz  16
#define Tz  1024
#define Cz  16
#define Dz  256
#define NHz 4
#define HDz 64
#define Lz  4
#define MROWS (Bz*Tz)   // 16384
#define QB  8           // attention q-rows per block

typedef _Float16 half8_t __attribute__((ext_vector_type(8)));
typedef float    f32x4_t __attribute__((ext_vector_type(4)));

__device__ __forceinline__ float sigmoidf_(float x){ return 1.0f/(1.0f+__expf(-x)); }
__device__ __forceinline__ float tanh_(float x){
  float e = __expf(2.f*x);
  return 1.f - 2.f/(e + 1.f);
}

// v_dot2_f32_f16: acc += a.x*b.x + a.y*b.y (f16 inputs, f32 accumulate)
__device__ __forceinline__ float dot2f(uint a, uint b, float c){
  float d;
  asm("v_dot2_f32_f16 %0, %1, %2, %3" : "=v"(d) : "v"(a), "v"(b), "v"(c));
  return d;
}
// pack two floats to half2 (RTE)
__device__ __forceinline__ uint f2h2(float a, float b){
  union { _Float16 h[2]; uint u; } r;
  r.h[0] = (_Float16)a; r.h[1] = (_Float16)b;
  return r.u;
}

// 8-lane all-reduce (R7-proven): xor1/xor2 via DPP quad_perm, xor4 via shfl
__device__ __forceinline__ float red8(float a){
  int x = __builtin_amdgcn_update_dpp(0, __float_as_int(a), 0xB1, 0xF, 0xF, true); // quad_perm[1,0,3,2]
  a += __int_as_float(x);
  x = __builtin_amdgcn_update_dpp(0, __float_as_int(a), 0x4E, 0xF, 0xF, true);     // quad_perm[2,3,0,1]
  a += __int_as_float(x);
  a += __shfl_xor(a, 4);
  return a;
}

// Raw barrier: order LDS handoff only (lgkmcnt) — never drain vmcnt, so the
// Whh DMA ring stays in flight across phases.
#define BARSYNC() do{ \
  asm volatile("s_waitcnt lgkmcnt(0)" ::: "memory"); \
  __builtin_amdgcn_s_barrier(); \
}while(0)

typedef const __attribute__((address_space(1))) void* as1p;
typedef __attribute__((address_space(3))) void* as3p;

// ---------------------------------------------------------------------------
// Prep: scan weights -> f16 pairs in (i, lane) layout (R7 layout).
// Also builds biasC[768] = gru_bih + [bhr|bhz|0].
// ---------------------------------------------------------------------------
__global__ __launch_bounds__(256) void k_prep(
    const float* __restrict__ W1, const float* __restrict__ W2, const float* __restrict__ Whh,
    const float* __restrict__ bih, const float* __restrict__ bhh,
    uint* __restrict__ W1L, uint* __restrict__ W2L, uint* __restrict__ WhL,
    float* __restrict__ biasC)
{
  int m = blockIdx.x*256 + threadIdx.x;
  if (m < 65536){
    const float* W = (m < 32768) ? W1 : W2;
    uint* out = (m < 32768) ? W1L : W2L;
    int mm = m & 32767;
    int q = mm >> 2, cc = mm & 3;
    int i = q >> 9, l = q & 511;
    int j4 = l >> 3, ks = l & 7;
    int kp = ks*16 + i;
    int c = j4*4 + cc;
    out[mm] = f2h2(W[(2*kp)*256 + c], W[(2*kp+1)*256 + c]);
  } else if (m < 65536 + 98304){
    int mm = m - 65536;
    int g = mm >> 15;          // gate plane
    int r = mm & 32767;
    int q = r >> 2, cc = r & 3;
    int i = q >> 9, l = q & 511;
    int j4 = l >> 3, ks = l & 7;
    int kp = ks*16 + i;
    int c = j4*4 + cc;
    WhL[mm] = f2h2(Whh[(2*kp)*768 + g*256 + c], Whh[(2*kp+1)*768 + g*256 + c]);
  } else if (m < 65536 + 98304 + 768){
    int c = m - (65536 + 98304);
    biasC[c] = bih[c] + ((c < 512) ? bhh[c] : 0.f);
  }
}

// ---------------------------------------------------------------------------
// Pack a weight matrix W[K][N] (f32, row-major) into MFMA fragment order:
// Wp[idx], idx = kr*N + col, kr in [0,K/8): uint4 = 8 f16 of
// W[kr*8+0..7][col].  Works for stacked per-layer weights (K mult of 32).
// ---------------------------------------------------------------------------
__global__ __launch_bounds__(256) void k_packw(
    const float* __restrict__ W, uint4* __restrict__ Wp, int N, int total)
{
  int idx = blockIdx.x*256 + threadIdx.x;
  if (idx >= total) return;
  int col = idx % N, kr = idx / N;
  size_t kb = (size_t)kr*8;
  uint4 o;
  o.x = f2h2(W[(kb+0)*N+col], W[(kb+1)*N+col]);
  o.y = f2h2(W[(kb+2)*N+col], W[(kb+3)*N+col]);
  o.z = f2h2(W[(kb+4)*N+col], W[(kb+5)*N+col]);
  o.w = f2h2(W[(kb+6)*N+col], W[(kb+7)*N+col]);
  Wp[idx] = o;
}

// ---------------------------------------------------------------------------
// K0: per-batch diffusion-step embedding te, FiLM gamma/beta.  grid=B, block=256
// ---------------------------------------------------------------------------
__global__ __launch_bounds__(256) void k_batch_emb(
    const int* __restrict__ t, const float* __restrict__ te_freqs,
    const float* __restrict__ W_temb, const float* __restrict__ b_temb,
    const float* __restrict__ W_film, const float* __restrict__ b_film,
    float* __restrict__ te_out, float* __restrict__ gamma_out, float* __restrict__ beta_out)
{
  int b = blockIdx.x; int j = threadIdx.x;
  __shared__ float s[256];
  __shared__ float ste[256];
  float tf = (float)t[b];
  if (j < 128){
    float targ = tf * te_freqs[j];
    s[j]     = __sinf(targ);
    s[j+128] = __cosf(targ);
  }
  __syncthreads();
  float a0=0,a1=0,a2=0,a3=0;
  #pragma unroll 8
  for (int k=0;k<256;k+=4){
    a0 = fmaf(s[k+0], W_temb[(k+0)*256+j], a0);
    a1 = fmaf(s[k+1], W_temb[(k+1)*256+j], a1);
    a2 = fmaf(s[k+2], W_temb[(k+2)*256+j], a2);
    a3 = fmaf(s[k+3], W_temb[(k+3)*256+j], a3);
  }
  float te = (a0+a1)+(a2+a3) + b_temb[j];
  te_out[b*256+j] = te;
  ste[j] = te * sigmoidf_(te);            // silu
  __syncthreads();
  float g0=0,g1=0,h0=0,h1=0;
  #pragma unroll 8
  for (int k=0;k<256;k+=2){
    float v0 = ste[k+0], v1 = ste[k+1];
    g0 = fmaf(v0, W_film[(k+0)*512+j],     g0);
    g1 = fmaf(v1, W_film[(k+1)*512+j],     g1);
    h0 = fmaf(v0, W_film[(k+0)*512+256+j], h0);
    h1 = fmaf(v1, W_film[(k+1)*512+256+j], h1);
  }
  gamma_out[b*256+j] = g0+g1 + b_film[j];
  beta_out [b*256+j] = h0+h1 + b_film[256+j];
}

// ---------------------------------------------------------------------------
// K1: H0 = sqrt(ab)*relu([x,mask]@W_enc+b) + sqrt(1-ab)*noise + te + FiLM(tm)
// ---------------------------------------------------------------------------
__global__ __launch_bounds__(256) void k_encode(
    const float* __restrict__ x, const float* __restrict__ mask, const float* __restrict__ noise,
    const int* __restrict__ t, const float* __restrict__ alpha_bar, const float* __restrict__ ts,
    const float* __restrict__ W_enc, const float* __restrict__ b_enc,
    const float* __restrict__ th_a, const float* __restrict__ th_b, const float* __restrict__ th_freqs,
    const float* __restrict__ te, const float* __restrict__ gamma, const float* __restrict__ beta,
    float* __restrict__ H0)
{
  int bt = blockIdx.x; int b = bt >> 10;
  int j = threadIdx.x;
  __shared__ float in[32];
  if (j < 16)      in[j] = x[bt*16 + j];
  else if (j < 32) in[j] = mask[bt*16 + (j-16)];
  __syncthreads();
  float acc = 0.f;
  #pragma unroll
  for (int k=0;k<32;k++) acc = fmaf(in[k], W_enc[k*256+j], acc);
  float z = fmaxf(acc + b_enc[j], 0.f);
  float ab = alpha_bar[t[b]];
  float h = sqrtf(ab)*z + sqrtf(1.f-ab)*noise[(size_t)bt*256 + j];
  float tsv = ts[bt];
  float tm;
  if (j & 1){
    int i = (j-1) >> 1;
    tm = fmaf(tsv, th_a[i], th_b[i]);
  } else {
    int m = j >> 2;
    float ph = tsv * th_freqs[m];
    tm = ((j & 3) == 0) ? __sinf(ph) : __cosf(ph);
  }
  tm = fmaf(1.f + gamma[b*256+j], tm, beta[b*256+j]);
  H0[(size_t)bt*256 + j] = h + te[b*256+j] + tm;
}

// ---------------------------------------------------------------------------
// MFMA GEMM: C = A(MxK,f32) @ W(KxN, pre-packed f16 frags) + bias [+relu][+res]
// 128x128 block tile, 4 waves (2x2), 64x64 per wave, K-step 32,
// v_mfma_f32_16x16x32_f16.  Layouts per guide §3 (HW-verified C/D).
// ---------------------------------------------------------------------------
template<bool RELU, bool RES>
__global__ __launch_bounds__(256) void k_gemm(
    const float* __restrict__ A, const uint4* __restrict__ Wp,
    const float* __restrict__ bias, const float* __restrict__ Rp,
    float* __restrict__ Cp, int M, int N, int K)
{
  __shared__ _Float16 Asl[128][40];   // row stride 80B -> 2-way banks (free)
  __shared__ uint4    Bsl[4][128];    // [kb][col] fragment-packed
  const int bn = blockIdx.x*128, bm = blockIdx.y*128;
  const int tid = threadIdx.x;
  const int lane = tid & 63, w = tid >> 6;
  const int wr = (w >> 1)*64, wc = (w & 1)*64;
  const int l15 = lane & 15, l4 = lane >> 4;
  f32x4_t acc[4][4] = {};
  for (int k0 = 0; k0 < K; k0 += 32){
    // stage A: 1024 coalesced float4 loads -> f16 rows
    #pragma unroll
    for (int i=0;i<4;i++){
      int idx = tid + i*256;
      int row = idx >> 3, q = idx & 7;
      const float4 a4 = *(const float4*)&A[(size_t)(bm+row)*K + k0 + q*4];
      uint2 pk; pk.x = f2h2(a4.x, a4.y); pk.y = f2h2(a4.z, a4.w);
      *(uint2*)&Asl[row][q*4] = pk;
    }
    // stage B: 512 coalesced uint4 copies (already fragment-packed)
    const uint4* wsrc = Wp + (size_t)(k0 >> 5)*4*N + bn;
    #pragma unroll
    for (int i=0;i<2;i++){
      int idx = tid + i*256;
      int kb = idx >> 7, col = idx & 127;
      Bsl[kb][col] = wsrc[(size_t)kb*N + col];
    }
    __syncthreads();
    half8_t bf[4];
    #pragma unroll
    for (int tn=0; tn<4; tn++)
      bf[tn] = *(const half8_t*)&Bsl[l4][wc + tn*16 + l15];
    #pragma unroll
    for (int tm=0; tm<4; tm++){
      half8_t af = *(const half8_t*)&Asl[wr + tm*16 + l15][l4*8];
      #pragma unroll
      for (int tn=0; tn<4; tn++)
        acc[tm][tn] = __builtin_amdgcn_mfma_f32_16x16x32_f16(af, bf[tn], acc[tm][tn], 0, 0, 0);
    }
    __syncthreads();
  }
  // epilogue: C/D mapping col=lane&15, row=(lane>>4)*4+reg  (guide §3)
  #pragma unroll
  for (int tm=0;tm<4;tm++){
    #pragma unroll
    for (int tn=0;tn<4;tn++){
      int col = bn + wc + tn*16 + l15;
      float bcol = bias[col];
      #pragma unroll
      for (int r=0;r<4;r++){
        int row = bm + wr + tm*16 + l4*4 + r;
        float v = acc[tm][tn][r] + bcol;
        if (RELU) v = fmaxf(v, 0.f);
        if (RES)  v += Rp[(size_t)row*N + col];
        Cp[(size_t)row*N + col] = v;
      }
    }
  }
}

// ---------------------------------------------------------------------------
// K3: Jump-ODE (Euler) + GRU scan.  grid=B, block=512.  (R15/R10 proven)
// ---------------------------------------------------------------------------
#define W1_BYTES   131072
#define RING_OFF   131072
#define RING_BYTES 24576          // 8 waves * 3 slots * 1024 B
#define V2_OFF     (RING_OFF + RING_BYTES)
#define SCAN_LDS_BYTES (V2_OFF + 1280)

#define DOT4V(WV, VW) { uint4 _w = (WV); \
  a0 = dot2f(_w.x, VW, a0); a1 = dot2f(_w.y, VW, a1); \
  a2 = dot2f(_w.z, VW, a2); a3 = dot2f(_w.w, VW, a3); }

#define MV16L(VB) { \
  uint4 q0=(VB)[ks5+0], q1=(VB)[ks5+1], q2=(VB)[ks5+2], q3=(VB)[ks5+3]; \
  DOT4V(w1s[0*512+tid], q0.x)  DOT4V(w1s[1*512+tid], q0.y)  DOT4V(w1s[2*512+tid], q0.z)  DOT4V(w1s[3*512+tid], q0.w)  \
  DOT4V(w1s[4*512+tid], q1.x)  DOT4V(w1s[5*512+tid], q1.y)  DOT4V(w1s[6*512+tid], q1.z)  DOT4V(w1s[7*512+tid], q1.w)  \
  DOT4V(w1s[8*512+tid], q2.x)  DOT4V(w1s[9*512+tid], q2.y)  DOT4V(w1s[10*512+tid], q2.z) DOT4V(w1s[11*512+tid], q2.w) \
  DOT4V(w1s[12*512+tid], q3.x) DOT4V(w1s[13*512+tid], q3.y) DOT4V(w1s[14*512+tid], q3.z) DOT4V(w1s[15*512+tid], q3.w) }

#define MV16R(W, VB) { \
  uint4 q0=(VB)[ks5+0], q1=(VB)[ks5+1], q2=(VB)[ks5+2], q3=(VB)[ks5+3]; \
  DOT4V(W[0], q0.x)  DOT4V(W[1], q0.y)  DOT4V(W[2], q0.z)  DOT4V(W[3], q0.w)  \
  DOT4V(W[4], q1.x)  DOT4V(W[5], q1.y)  DOT4V(W[6], q1.z)  DOT4V(W[7], q1.w)  \
  DOT4V(W[8], q2.x)  DOT4V(W[9], q2.y)  DOT4V(W[10], q2.z) DOT4V(W[11], q2.w) \
  DOT4V(W[12], q3.x) DOT4V(W[13], q3.y) DOT4V(W[14], q3.z) DOT4V(W[15], q3.w) }

#define RING_STEP(S, N, G0,G1,G2,G3) { \
  asm volatile("s_waitcnt vmcnt(" #N ")" ::: "memory"); \
  uint4 wv = *(const uint4*)(ringRd + (((S)%3)<<10) + lane16); \
  G0 = dot2f(wv.x, vw[(S)&15], G0); G1 = dot2f(wv.y, vw[(S)&15], G1); \
  G2 = dot2f(wv.z, vw[(S)&15], G2); G3 = dot2f(wv.w, vw[(S)&15], G3); \
  __builtin_amdgcn_global_load_lds((as1p)(WhL4 + ((((S)+3)%48)<<9) + tid), \
                                   (as3p)(ringRd + (((S)%3)<<10)), 16, 0, 0); \
}

__global__ __launch_bounds__(512) void k_scan(
    const uint* __restrict__ W1Lg, const uint* __restrict__ W2Lg, const uint* __restrict__ WhLg,
    const float* __restrict__ GI, const float* __restrict__ ts,
    const float* __restrict__ b1, const float* __restrict__ b2,
    const float* __restrict__ bhh, float* __restrict__ Hseq)
{
  extern __shared__ __align__(16) char smem[];
  uint4* w1s = (uint4*)smem;                 // 128 KB, W1 resident
  uint*  v2  = (uint*)(smem + V2_OFF);       // 2 x 8 chunks x (16 data + 4 pad)
  const int b = blockIdx.x, tid = threadIdx.x;
  const int j4 = tid >> 3, ks = tid & 7;
  const int ks5 = ks*5;
  char* ringRd = smem + RING_OFF + (tid >> 6)*3072;   // per-wave 3-slot ring
  const int lane16 = (tid & 63) << 4;
  const uint4* W1L4 = (const uint4*)W1Lg;
  const uint4* W2L4 = (const uint4*)W2Lg;
  const uint4* WhL4 = (const uint4*)WhLg;
  #pragma unroll
  for (int i=0;i<16;i++) w1s[i*512+tid] = W1L4[i*512+tid];
  uint4 w2r[16];
  #pragma unroll
  for (int i=0;i<16;i++) w2r[i] = W2L4[i*512 + tid];
  if (tid < 320) v2[tid] = 0u;
  const float4 b1v  = ((const float4*)b1)[j4];
  const float4 b2v  = ((const float4*)b2)[j4];
  const float4 bhnv = ((const float4*)bhh)[128 + j4];
  const float* tsb = ts + b*Tz;
  const float* gib = GI + (size_t)b*Tz*768;
  float* hsq = Hseq + (size_t)b*Tz*256;
  const int wdw = 2*j4;
  const int wslot = (wdw >> 4)*20 + (wdw & 15);
  float4 h = {0.f,0.f,0.f,0.f};
  int cur = 0;
  float tprev = 0.f;
  __syncthreads();   // full drain OK here (before any ring DMA)

  #pragma unroll
  for (int s=0;s<3;s++)
    __builtin_amdgcn_global_load_lds((as1p)(WhL4 + (s<<9) + tid),
                                     (as3p)(ringRd + (s<<10)), 16, 0, 0);
  float4 gi_r = *(const float4*)(gib + 0*768       + j4*4);
  float4 gi_z = *(const float4*)(gib + 0*768 + 256 + j4*4);
  float4 gi_n = *(const float4*)(gib + 0*768 + 512 + j4*4);

  for (int tt=0; tt<Tz; ++tt){
    float tcur = tsb[tt];
    float dt = tcur - tprev; if (tt == 0) dt = 0.f;
    tprev = tcur;
    uint* bufA = v2 + (cur ? 160 : 0);
    uint* bufB = v2 + (cur ? 0 : 160);
    const uint4* vbA = (const uint4*)bufA;
    const uint4* vbB = (const uint4*)bufB;

    // ---- P1: u = tanh(W1·h + b1) -> B ----
    {
      float a0=0,a1=0,a2=0,a3=0;
      MV16L(vbA);
      a0=red8(a0); a1=red8(a1); a2=red8(a2); a3=red8(a3);
      float u0 = tanh_(a0+b1v.x), u1 = tanh_(a1+b1v.y);
      float u2 = tanh_(a2+b1v.z), u3 = tanh_(a3+b1v.w);
      if (ks == 0){
        uint2 pk; pk.x = f2h2(u0,u1); pk.y = f2h2(u2,u3);
        *(uint2*)(bufB + wslot) = pk;
      }
    }
    BARSYNC();
    // ---- P2: f = W2·u + b2 ; hnew = h + dt·f -> A ----
    float4 hn;
    {
      float a0=0,a1=0,a2=0,a3=0;
      MV16R(w2r, vbB);
      a0=red8(a0); a1=red8(a1); a2=red8(a2); a3=red8(a3);
      hn.x = fmaf(dt, a0+b2v.x, h.x);
      hn.y = fmaf(dt, a1+b2v.y, h.y);
      hn.z = fmaf(dt, a2+b2v.z, h.z);
      hn.w = fmaf(dt, a3+b2v.w, h.w);
      if (ks == 0){
        uint2 pk; pk.x = f2h2(hn.x,hn.y); pk.y = f2h2(hn.z,hn.w);
        *(uint2*)(bufA + wslot) = pk;
      }
    }
    BARSYNC();
    // ---- P5: gh = Whh·hnew via DMA ring ; h update -> B ----
    {
      uint4 q0=vbA[ks5+0], q1=vbA[ks5+1], q2=vbA[ks5+2], q3=vbA[ks5+3];
      uint vw[16] = {q0.x,q0.y,q0.z,q0.w, q1.x,q1.y,q1.z,q1.w,
                     q2.x,q2.y,q2.z,q2.w, q3.x,q3.y,q3.z,q3.w};
      float r0=0,r1=0,r2=0,r3=0, z0=0,z1=0,z2=0,z3=0, n0=0,n1=0,n2=0,n3=0;
      RING_STEP(0,3, r0,r1,r2,r3)  RING_STEP(1,3, r0,r1,r2,r3)
      RING_STEP(2,3, r0,r1,r2,r3)  RING_STEP(3,2, r0,r1,r2,r3)
      RING_STEP(4,2, r0,r1,r2,r3)  RING_STEP(5,2, r0,r1,r2,r3)
      RING_STEP(6,2, r0,r1,r2,r3)  RING_STEP(7,2, r0,r1,r2,r3)
      RING_STEP(8,2, r0,r1,r2,r3)  RING_STEP(9,2, r0,r1,r2,r3)
      RING_STEP(10,2, r0,r1,r2,r3) RING_STEP(11,2, r0,r1,r2,r3)
      RING_STEP(12,2, r0,r1,r2,r3) RING_STEP(13,2, r0,r1,r2,r3)
      RING_STEP(14,2, r0,r1,r2,r3) RING_STEP(15,2, r0,r1,r2,r3)
      RING_STEP(16,2, z0,z1,z2,z3) RING_STEP(17,2, z0,z1,z2,z3)
      RING_STEP(18,2, z0,z1,z2,z3) RING_STEP(19,2, z0,z1,z2,z3)
      RING_STEP(20,2, z0,z1,z2,z3) RING_STEP(21,2, z0,z1,z2,z3)
      RING_STEP(22,2, z0,z1,z2,z3) RING_STEP(23,2, z0,z1,z2,z3)
      RING_STEP(24,2, z0,z1,z2,z3) RING_STEP(25,2, z0,z1,z2,z3)
      RING_STEP(26,2, z0,z1,z2,z3) RING_STEP(27,2, z0,z1,z2,z3)
      RING_STEP(28,2, z0,z1,z2,z3) RING_STEP(29,2, z0,z1,z2,z3)
      RING_STEP(30,2, z0,z1,z2,z3) RING_STEP(31,2, z0,z1,z2,z3)
      RING_STEP(32,2, n0,n1,n2,n3) RING_STEP(33,2, n0,n1,n2,n3)
      RING_STEP(34,2, n0,n1,n2,n3) RING_STEP(35,2, n0,n1,n2,n3)
      RING_STEP(36,2, n0,n1,n2,n3) RING_STEP(37,2, n0,n1,n2,n3)
      RING_STEP(38,2, n0,n1,n2,n3) RING_STEP(39,2, n0,n1,n2,n3)
      RING_STEP(40,2, n0,n1,n2,n3) RING_STEP(41,2, n0,n1,n2,n3)
      RING_STEP(42,2, n0,n1,n2,n3) RING_STEP(43,2, n0,n1,n2,n3)
      RING_STEP(44,2, n0,n1,n2,n3)
      int ttn = (tt+1 < Tz) ? tt+1 : Tz-1;
      float4 ngi_r = *(const float4*)(gib + ttn*768       + j4*4);
      float4 ngi_z = *(const float4*)(gib + ttn*768 + 256 + j4*4);
      float4 ngi_n = *(const float4*)(gib + ttn*768 + 512 + j4*4);
      RING_STEP(45,2, n0,n1,n2,n3) RING_STEP(46,2, n0,n1,n2,n3)
      RING_STEP(47,2, n0,n1,n2,n3)
      r0=red8(r0); r1=red8(r1); r2=red8(r2); r3=red8(r3);
      z0=red8(z0); z1=red8(z1); z2=red8(z2); z3=red8(z3);
      n0=red8(n0); n1=red8(n1); n2=red8(n2); n3=red8(n3);
      float gr0 = sigmoidf_(gi_r.x + r0);
      float gr1 = sigmoidf_(gi_r.y + r1);
      float gr2 = sigmoidf_(gi_r.z + r2);
      float gr3 = sigmoidf_(gi_r.w + r3);
      float gz0 = sigmoidf_(gi_z.x + z0);
      float gz1 = sigmoidf_(gi_z.y + z1);
      float gz2 = sigmoidf_(gi_z.z + z2);
      float gz3 = sigmoidf_(gi_z.w + z3);
      float gn0 = tanh_(gi_n.x + gr0*(n0 + bhnv.x));
      float gn1 = tanh_(gi_n.y + gr1*(n1 + bhnv.y));
      float gn2 = tanh_(gi_n.z + gr2*(n2 + bhnv.z));
      float gn3 = tanh_(gi_n.w + gr3*(n3 + bhnv.w));
      h.x = fmaf(gz0, hn.x - gn0, gn0);
      h.y = fmaf(gz1, hn.y - gn1, gn1);
      h.z = fmaf(gz2, hn.z - gn2, gn2);
      h.w = fmaf(gz3, hn.w - gn3, gn3);
      gi_r = ngi_r; gi_z = ngi_z; gi_n = ngi_n;
      if (ks == 0){
        uint2 pk; pk.x = f2h2(h.x,h.y); pk.y = f2h2(h.z,h.w);
        *(uint2*)(bufB + wslot) = pk;
        *(float4*)(hsq + tt*256 + j4*4) = h;
      }
    }
    cur ^= 1;
    BARSYNC();
  }
}

// ---------------------------------------------------------------------------
// K6: causal attention, one (b,h,q-block of 8).  f16-dot2 scores, float4 PV.
// ---------------------------------------------------------------------------
__global__ __launch_bounds__(256) void k_attn(const float* __restrict__ QKV, float* __restrict__ O)
{
  int qb = blockIdx.x & (Tz/QB - 1);
  int bh = blockIdx.x / (Tz/QB);
  int b = bh >> 2, h = bh & 3;
  __shared__ uint Q2[QB][32];
  __shared__ float S[QB][Tz];
  __shared__ __align__(16) char kvbuf[64*68*4];
  __shared__ float rs[QB];
  uint  (*K2)[33] = (uint(*)[33])kvbuf;
  float (*Vs)[68] = (float(*)[68])kvbuf;
  int tid = threadIdx.x;
  const float* base = QKV + (size_t)b*Tz*768;
  for (int i = tid; i < QB*16; i += 256){
    int q = i >> 4, c = i & 15;
    const float4 v = *(const float4*)&base[(size_t)(qb*QB+q)*768 + h*64 + c*4];
    Q2[q][c*2]   = f2h2(v.x*0.125f, v.y*0.125f);
    Q2[q][c*2+1] = f2h2(v.z*0.125f, v.w*0.125f);
  }
  __syncthreads();
  int kmax = qb*QB + QB;
  int nkt = (kmax + 63) >> 6;
  int q = tid >> 5, i0 = tid & 31;
  int qg = qb*QB + q;
  for (int kt=0; kt<nkt; ++kt){
    for (int i=tid; i<64*16; i+=256){
      int r=i>>4, c=i&15;
      const float4 v = *(const float4*)&base[(size_t)(kt*64+r)*768 + 256 + h*64 + c*4];
      K2[r][c*2]   = f2h2(v.x, v.y);
      K2[r][c*2+1] = f2h2(v.z, v.w);
    }
    __syncthreads();
    float a0=0.f, a1=0.f;
    #pragma unroll 8
    for (int dp=0; dp<32; ++dp){
      uint qv = Q2[q][dp];
      a0 = dot2f(K2[i0][dp],    qv, a0);
      a1 = dot2f(K2[i0+32][dp], qv, a1);
    }
    int k0g = kt*64 + i0, k1g = k0g + 32;
    S[q][kt*64+i0]    = (k0g <= qg) ? a0 : -1e30f;
    S[q][kt*64+i0+32] = (k1g <= qg) ? a1 : -1e30f;
    __syncthreads();
  }
  int NK = nkt*64;
  float m = -1e30f;
  for (int kk=i0; kk<NK; kk+=32) m = fmaxf(m, S[q][kk]);
  #pragma unroll
  for (int o=16;o;o>>=1) m = fmaxf(m, __shfl_xor(m, o, 32));
  float sum = 0.f;
  for (int kk=i0; kk<NK; kk+=32){
    float p = __expf(S[q][kk] - m);
    S[q][kk] = p;
    sum += p;
  }
  #pragma unroll
  for (int o=16;o;o>>=1) sum += __shfl_xor(sum, o, 32);
  if (i0 == 0) rs[q] = 1.f/sum;
  int dq = tid & 15;
  int ks = (tid >> 4) & 1;
  float o0=0,o1=0,o2=0,o3=0;
  for (int kt=0; kt<nkt; ++kt){
    __syncthreads();
    for (int i=tid; i<64*16; i+=256){
      int r=i>>4, c=i&15;
      const float4 v = *(const float4*)&base[(size_t)(kt*64+r)*768 + 512 + h*64 + c*4];
      *(float4*)&Vs[r][c*4] = v;
    }
    __syncthreads();
    int kbase = kt*64;
    #pragma unroll 8
    for (int kk=ks; kk<64; kk+=2){
      float p = S[q][kbase+kk];
      const float4 vv = *(const float4*)&Vs[kk][dq*4];
      o0=fmaf(p,vv.x,o0); o1=fmaf(p,vv.y,o1); o2=fmaf(p,vv.z,o2); o3=fmaf(p,vv.w,o3);
    }
  }
  o0 += __shfl_xor(o0, 16); o1 += __shfl_xor(o1, 16);
  o2 += __shfl_xor(o2, 16); o3 += __shfl_xor(o3, 16);
  if (!(tid & 16)){
    float r = rs[q];
    size_t orow = ((size_t)b*Tz + qg)*256 + h*64 + dq*4;
    float4 ov = {o0*r, o1*r, o2*r, o3*r};
    *(float4*)&O[orow] = ov;
  }
}

// ---------------------------------------------------------------------------
// LayerNorm over D=256.
// ---------------------------------------------------------------------------
template<bool FINAL>
__global__ __launch_bounds__(256) void k_ln(
    const float* __restrict__ in, const float* __restrict__ w, const float* __restrict__ bgain,
    const float* __restrict__ addv, float* __restrict__ out)
{
  int row  = blockIdx.x*4 + (threadIdx.x >> 6);
  int lane = threadIdx.x & 63;
  const float4 xv = ((const float4*)(in + (size_t)row*256))[lane];
  float s = xv.x + xv.y + xv.z + xv.w;
  #pragma unroll
  for (int o=32;o;o>>=1) s += __shfl_xor(s, o, 64);
  float mean = s * (1.f/256.f);
  float dx=xv.x-mean, dy=xv.y-mean, dz=xv.z-mean, dw=xv.w-mean;
  float qv = dx*dx + dy*dy + dz*dz + dw*dw;
  #pragma unroll
  for (int o=32;o;o>>=1) qv += __shfl_xor(qv, o, 64);
  float rstd = 1.f/sqrtf(qv*(1.f/256.f) + 1e-5f);
  const float4 wv = ((const float4*)w)[lane];
  const float4 bv = ((const float4*)bgain)[lane];
  float4 ov;
  ov.x = dx*rstd*wv.x + bv.x;
  ov.y = dy*rstd*wv.y + bv.y;
  ov.z = dz*rstd*wv.z + bv.z;
  ov.w = dw*rstd*wv.w + bv.w;
  if (FINAL){
    const float4 av = ((const float4*)(addv + (size_t)row*256))[lane];
    ov.x += av.x; ov.y += av.y; ov.z += av.z; ov.w += av.w;
  }
  ((float4*)(out + (size_t)row*256))[lane] = ov;
}

// ---------------------------------------------------------------------------
extern "C" void kernel_launch(void* const* d_in, const int* in_sizes, int n_in,
                              void* d_out, int out_size, void* d_ws, size_t ws_size,
                              hipStream_t stream)
{
  const float* x         = (const float*)d_in[0];
  const int*   t         = (const int*)  d_in[1];
  const float* ts        = (const float*)d_in[2];
  const float* mask      = (const float*)d_in[3];
  const float* noise     = (const float*)d_in[4];
  const float* alpha_bar = (const float*)d_in[6];
  const float* W_enc     = (const float*)d_in[7];
  const float* b_enc     = (const float*)d_in[8];
  const float* te_freqs  = (const float*)d_in[9];
  const float* W_temb    = (const float*)d_in[10];
  const float* b_temb    = (const float*)d_in[11];
  const float* th_a      = (const float*)d_in[12];
  const float* th_b      = (const float*)d_in[13];
  const float* th_freqs  = (const float*)d_in[14];
  const float* W_film    = (const float*)d_in[15];
  const float* b_film    = (const float*)d_in[16];
  const float* gru_Wih   = (const float*)d_in[17];
  const float* gru_Whh   = (const float*)d_in[18];
  const float* gru_bih   = (const float*)d_in[19];
  const float* gru_bhh   = (const float*)d_in[20];
  const float* ode_W1    = (const float*)d_in[21];
  const float* ode_b1    = (const float*)d_in[22];
  const float* ode_W2    = (const float*)d_in[23];
  const float* ode_b2    = (const float*)d_in[24];
  const float* tr_Wqkv   = (const float*)d_in[25];
  const float* tr_bqkv   = (const float*)d_in[26];
  const float* tr_Wo     = (const float*)d_in[27];
  const float* tr_bo     = (const float*)d_in[28];
  const float* tr_ln1_w  = (const float*)d_in[29];
  const float* tr_ln1_b  = (const float*)d_in[30];
  const float* tr_ln2_w  = (const float*)d_in[31];
  const float* tr_ln2_b  = (const float*)d_in[32];
  const float* tr_W1     = (const float*)d_in[33];
  const float* tr_b1     = (const float*)d_in[34];
  const float* tr_W2     = (const float*)d_in[35];
  const float* tr_b2     = (const float*)d_in[36];
  const float* trn_w     = (const float*)d_in[37];
  const float* trn_b     = (const float*)d_in[38];

  float* w = (float*)d_ws;
  float* te    = w;
  float* gamma = w + 4096;
  float* beta  = w + 8192;
  float* R1    = w + 12288;                 // 16M floats, multi-use
  float* H0    = R1;
  float* GI    = R1 + 4*1024*1024;
  float* QKVb  = R1;
  float* F1    = R1;
  float* Hseq  = R1   + 16*1024*1024;
  float* Ht    = Hseq + 4*1024*1024;
  float* U     = Ht   + 4*1024*1024;
  float* O     = U    + 4*1024*1024;
  uint*  W1L   = (uint*)(O + 4*1024*1024);  // 32768 u32
  uint*  W2L   = W1L + 32768;               // 32768 u32
  uint*  WhL   = W2L + 32768;               // 98304 u32
  float* biasC = (float*)(WhL + 98304);     // 768 floats

  // MFMA weight packs live in d_out (free scratch until the final LN,
  // which overwrites all of d_out afterwards).
  uint4* WihP  = (uint4*)d_out;             // 24576 uint4
  uint4* WqkvP = WihP  + 24576;             // 98304
  uint4* WoP   = WqkvP + 98304;             // 32768
  uint4* W1P   = WoP   + 32768;             // 131072
  uint4* W2P   = W1P   + 131072;            // 131072  (total 6.7 MB < 16 MB)

  // Phase A
  k_prep<<<643, 256, 0, stream>>>(ode_W1, ode_W2, gru_Whh, gru_bih, gru_bhh,
                                  W1L, W2L, WhL, biasC);
  k_packw<<<96,  256, 0, stream>>>(gru_Wih, WihP, 768, 24576);
  k_packw<<<384, 256, 0, stream>>>(tr_Wqkv, WqkvP, 768, 98304);
  k_packw<<<128, 256, 0, stream>>>(tr_Wo,   WoP,   256, 32768);
  k_packw<<<512, 256, 0, stream>>>(tr_W1,   W1P,  1024, 131072);
  k_packw<<<512, 256, 0, stream>>>(tr_W2,   W2P,   256, 131072);
  k_batch_emb<<<Bz, 256, 0, stream>>>(t, te_freqs, W_temb, b_temb, W_film, b_film, te, gamma, beta);
  k_encode<<<MROWS, 256, 0, stream>>>(x, mask, noise, t, alpha_bar, ts, W_enc, b_enc,
                                      th_a, th_b, th_freqs, te, gamma, beta, H0);
  k_gemm<false,false><<<dim3(768/128, MROWS/128), 256, 0, stream>>>(H0, WihP, biasC, nullptr, GI, MROWS, 768, 256);

  // Phase B: scan (153.25 KB dynamic LDS)
  hipFuncSetAttribute((const void*)k_scan, hipFuncAttributeMaxDynamicSharedMemorySize, SCAN_LDS_BYTES);
  k_scan<<<Bz, 512, SCAN_LDS_BYTES, stream>>>(W1L, W2L, WhL, GI, ts, ode_b1, ode_b2, gru_bhh, Hseq);

  // Phase C  (layer 0 reads Hseq directly; Ht produced by the first RES gemm)
  for (int l=0; l<Lz; ++l){
    const float* Hin = (l == 0) ? Hseq : Ht;
    k_ln<false><<<MROWS/4, 256, 0, stream>>>(Hin, tr_ln1_w + l*256, tr_ln1_b + l*256, nullptr, U);
    k_gemm<false,false><<<dim3(768/128, MROWS/128), 256, 0, stream>>>(U, WqkvP + (size_t)l*24576, tr_bqkv + l*768, nullptr, QKVb, MROWS, 768, 256);
    k_attn<<<Bz*NHz*(Tz/QB), 256, 0, stream>>>(QKVb, O);
    k_gemm<false,true><<<dim3(256/128, MROWS/128), 256, 0, stream>>>(O, WoP + (size_t)l*8192, tr_bo + l*256, Hin, Ht, MROWS, 256, 256);
    k_ln<false><<<MROWS/4, 256, 0, stream>>>(Ht, tr_ln2_w + l*256, tr_ln2_b + l*256, nullptr, U);
    k_gemm<true,false><<<dim3(1024/128, MROWS/128), 256, 0, stream>>>(U, W1P + (size_t)l*32768, tr_b1 + l*1024, nullptr, F1, MROWS, 1024, 256);
    k_gemm<false,true><<<dim3(256/128, MROWS/128), 256, 0, stream>>>(F1, W2P + (size_t)l*32768, tr_b2 + l*256, Ht, Ht, MROWS, 256, 1024);
  }

  k_ln<true><<<MROWS/4, 256, 0, stream>>>(Ht, trn_w, trn_b, Hseq, (float*)d_out);
}